// Round 1
// baseline (302.281 us; speedup 1.0000x reference)
//
#include <hip/hip_runtime.h>
#include <math.h>

#define NPTS 512
#define DIM  768
#define KNN  64
#define NH   8
#define HDIM 96
#define MROWS 1024   // B*NP

// ---------------------------------------------------------------------------
// Kernel 1: fold distance-encoder through Wk/Wv:
//   wdk = Wd @ Wk, ck = bd @ Wk + bk, wdv = Wd @ Wv, cv = bd @ Wv + bv
// ---------------------------------------------------------------------------
__global__ __launch_bounds__(256) void prep_vecs_k(
    const float* __restrict__ Wd, const float* __restrict__ bd,
    const float* __restrict__ Wk, const float* __restrict__ bk,
    const float* __restrict__ Wv, const float* __restrict__ bv,
    float* __restrict__ wdk, float* __restrict__ ck,
    float* __restrict__ wdv, float* __restrict__ cv)
{
    int n = blockIdx.x * 256 + threadIdx.x;
    if (n >= DIM) return;
    float a = 0.f, b = 0.f, c = 0.f, d = 0.f;
    for (int k = 0; k < DIM; ++k) {
        float wd = Wd[k], bdk = bd[k];
        float wkv = Wk[k * DIM + n], wvv = Wv[k * DIM + n];
        a += wd * wkv; b += bdk * wkv;
        c += wd * wvv; d += bdk * wvv;
    }
    wdk[n] = a; ck[n] = b + bk[n];
    wdv[n] = c; cv[n] = d + bv[n];
}

// ---------------------------------------------------------------------------
// Kernel 2: per-point pairwise distance + top-64 (bitonic sort of 512 keys).
// Key = (float_bits(dist) << 32) | index  -> ascending sort == nearest first,
// ties broken by smaller index (matches jax.lax.top_k stability; neighbor SET
// is all that matters since softmax over K is permutation-invariant).
// ---------------------------------------------------------------------------
__global__ __launch_bounds__(256) void topk_k(
    const float* __restrict__ pts, int* __restrict__ idxb, float* __restrict__ distb)
{
    int bn = blockIdx.x;            // 0..1023
    int b  = bn >> 9;
    int n  = bn & (NPTS - 1);
    __shared__ float P[NPTS * 3];
    __shared__ unsigned long long keys[NPTS];
    const float* pb = pts + (size_t)b * NPTS * 3;
    for (int i = threadIdx.x; i < NPTS * 3; i += 256) P[i] = pb[i];
    __syncthreads();
    float xn = P[n * 3], yn = P[n * 3 + 1], zn = P[n * 3 + 2];
    float sqn = xn * xn + yn * yn + zn * zn;
    for (int m = threadIdx.x; m < NPTS; m += 256) {
        float xm = P[m * 3], ym = P[m * 3 + 1], zm = P[m * 3 + 2];
        float sqm = xm * xm + ym * ym + zm * zm;
        float d2 = sqn + sqm - 2.0f * (xn * xm + yn * ym + zn * zm);
        float dist = sqrtf(fmaxf(d2, 0.0f));
        keys[m] = (((unsigned long long)__float_as_uint(dist)) << 32) | (unsigned)m;
    }
    __syncthreads();
    for (int k = 2; k <= NPTS; k <<= 1) {
        for (int j = k >> 1; j > 0; j >>= 1) {
            for (int i = threadIdx.x; i < NPTS; i += 256) {
                int ixj = i ^ j;
                if (ixj > i) {
                    bool asc = ((i & k) == 0);
                    unsigned long long a = keys[i], bb = keys[ixj];
                    if ((a > bb) == asc) { keys[i] = bb; keys[ixj] = a; }
                }
            }
            __syncthreads();
        }
    }
    if (threadIdx.x < KNN) {
        unsigned long long kk = keys[threadIdx.x];
        idxb[(size_t)bn * KNN + threadIdx.x]  = (int)(kk & 0xffffffffu);
        distb[(size_t)bn * KNN + threadIdx.x] = __uint_as_float((unsigned)(kk >> 32));
    }
}

// ---------------------------------------------------------------------------
// Kernel 3: generic fp32 GEMM  C[z] = A @ W[z] (+bias[z]) (+= if acc)
// A: [M,K] row-major, W: [K,N] row-major, C: [M,N]. 64x64 block tile,
// 256 threads, 4x4 per thread, K-tile 16.
// ---------------------------------------------------------------------------
__global__ __launch_bounds__(256) void gemm64_k(
    const float* __restrict__ A,
    const float* __restrict__ W0, const float* __restrict__ W1, const float* __restrict__ W2,
    const float* __restrict__ b0, const float* __restrict__ b1, const float* __restrict__ b2,
    float* __restrict__ C0, float* __restrict__ C1, float* __restrict__ C2,
    int M, int N, int Kd, int accflag)
{
    const float* W    = (blockIdx.z == 0) ? W0 : (blockIdx.z == 1) ? W1 : W2;
    const float* bias = (blockIdx.z == 0) ? b0 : (blockIdx.z == 1) ? b1 : b2;
    float*       C    = (blockIdx.z == 0) ? C0 : (blockIdx.z == 1) ? C1 : C2;

    __shared__ float As[16][68];   // [k][m], +4 pad keeps float4 alignment
    __shared__ float Ws[16][64];   // [k][n]

    int tid = threadIdx.x;
    int tx = tid & 15, ty = tid >> 4;
    int brow = blockIdx.y * 64, bcol = blockIdx.x * 64;

    float accr[4][4] = {{0.f}};

    int am = tid >> 2, ak = (tid & 3) << 2;  // A: 64 rows x 16 k, float4 each
    int wc = tid & 63, wr = tid >> 6;        // W: 16 rows x 64 cols

    for (int k0 = 0; k0 < Kd; k0 += 16) {
        float4 av = *(const float4*)&A[(size_t)(brow + am) * Kd + k0 + ak];
        As[ak + 0][am] = av.x; As[ak + 1][am] = av.y;
        As[ak + 2][am] = av.z; As[ak + 3][am] = av.w;
#pragma unroll
        for (int i = 0; i < 4; ++i)
            Ws[wr + i * 4][wc] = W[(size_t)(k0 + wr + i * 4) * N + bcol + wc];
        __syncthreads();
#pragma unroll
        for (int kk = 0; kk < 16; ++kk) {
            float4 a4 = *(const float4*)&As[kk][ty * 4];
            float4 b4 = *(const float4*)&Ws[kk][tx * 4];
            float ar[4] = {a4.x, a4.y, a4.z, a4.w};
            float br[4] = {b4.x, b4.y, b4.z, b4.w};
#pragma unroll
            for (int i = 0; i < 4; ++i)
#pragma unroll
                for (int j = 0; j < 4; ++j)
                    accr[i][j] = fmaf(ar[i], br[j], accr[i][j]);
        }
        __syncthreads();
    }

#pragma unroll
    for (int i = 0; i < 4; ++i) {
        int row = brow + ty * 4 + i;
        int col = bcol + tx * 4;
        float4 o;
        o.x = accr[i][0]; o.y = accr[i][1]; o.z = accr[i][2]; o.w = accr[i][3];
        if (bias) {
            o.x += bias[col]; o.y += bias[col + 1];
            o.z += bias[col + 2]; o.w += bias[col + 3];
        }
        float* cp = &C[(size_t)row * N + col];
        if (accflag) {
            float4 p = *(const float4*)cp;
            o.x += p.x; o.y += p.y; o.z += p.z; o.w += p.w;
        }
        *(float4*)cp = o;
    }
}

// ---------------------------------------------------------------------------
// Kernel 4: fused neighbor attention. One block per (b,n). 256 threads,
// thread t owns output elems [3t,3t+3) -> head h = t/32, 32 threads/head.
//   score_j = (q . FK[idx_j] + dist_j*(q.wdk) + (q.ck)) / sqrt(96)
//   o = sum_j attn_j*FV[idx_j] + (sum_j attn_j*dist_j)*wdv + cv
// ---------------------------------------------------------------------------
__global__ __launch_bounds__(256) void attn_k(
    const float* __restrict__ FQ, const float* __restrict__ FK, const float* __restrict__ FV,
    const int* __restrict__ idxb, const float* __restrict__ distb,
    const float* __restrict__ wdk, const float* __restrict__ ck,
    const float* __restrict__ wdv, const float* __restrict__ cv,
    float* __restrict__ O)
{
    int bn = blockIdx.x;
    int b  = bn >> 9;
    int tid = threadIdx.x;
    int h = tid >> 5;
    int lane32 = tid & 31;

    __shared__ int   s_idx[KNN];
    __shared__ float s_dist[KNN];
    __shared__ float s_sc[NH][KNN];
    __shared__ float s_att[NH][KNN];
    __shared__ float s_qh[NH][2];
    __shared__ float s_sd[NH];

    if (tid < KNN) {
        s_idx[tid]  = idxb[(size_t)bn * KNN + tid];
        s_dist[tid] = distb[(size_t)bn * KNN + tid];
    }

    int e0 = tid * 3;
    const float* qrow = FQ + (size_t)bn * DIM;
    float q0 = qrow[e0], q1 = qrow[e0 + 1], q2 = qrow[e0 + 2];

    float pw = q0 * wdk[e0] + q1 * wdk[e0 + 1] + q2 * wdk[e0 + 2];
    float pc = q0 * ck[e0]  + q1 * ck[e0 + 1]  + q2 * ck[e0 + 2];
#pragma unroll
    for (int off = 16; off; off >>= 1) {
        pw += __shfl_xor(pw, off);
        pc += __shfl_xor(pc, off);
    }
    if (lane32 == 0) { s_qh[h][0] = pw; s_qh[h][1] = pc; }
    __syncthreads();

    float qwdk = s_qh[h][0], qck = s_qh[h][1];
    const float invs = 0.10206207261596575f;  // 1/sqrt(96)
    int base = b * NPTS;

    for (int j = 0; j < KNN; ++j) {
        const float* kr = FK + (size_t)(base + s_idx[j]) * DIM;
        float p = q0 * kr[e0] + q1 * kr[e0 + 1] + q2 * kr[e0 + 2];
#pragma unroll
        for (int off = 16; off; off >>= 1) p += __shfl_xor(p, off);
        if (lane32 == 0) s_sc[h][j] = (p + s_dist[j] * qwdk + qck) * invs;
    }
    __syncthreads();

    // softmax over 64 per head (each of 32 threads owns 2 scores)
    float s0 = s_sc[h][lane32], s1 = s_sc[h][lane32 + 32];
    float mx = fmaxf(s0, s1);
#pragma unroll
    for (int off = 16; off; off >>= 1) mx = fmaxf(mx, __shfl_xor(mx, off));
    float ev0 = __expf(s0 - mx), ev1 = __expf(s1 - mx);
    float sum = ev0 + ev1;
#pragma unroll
    for (int off = 16; off; off >>= 1) sum += __shfl_xor(sum, off);
    float rs = 1.0f / sum;
    float a0 = ev0 * rs, a1 = ev1 * rs;
    s_att[h][lane32] = a0; s_att[h][lane32 + 32] = a1;
    float sd = a0 * s_dist[lane32] + a1 * s_dist[lane32 + 32];
#pragma unroll
    for (int off = 16; off; off >>= 1) sd += __shfl_xor(sd, off);
    if (lane32 == 0) s_sd[h] = sd;
    __syncthreads();

    float o0 = 0.f, o1 = 0.f, o2 = 0.f;
    for (int j = 0; j < KNN; ++j) {
        const float* vr = FV + (size_t)(base + s_idx[j]) * DIM;
        float a = s_att[h][j];
        o0 = fmaf(a, vr[e0], o0);
        o1 = fmaf(a, vr[e0 + 1], o1);
        o2 = fmaf(a, vr[e0 + 2], o2);
    }
    float sdh = s_sd[h];
    o0 += sdh * wdv[e0]     + cv[e0];
    o1 += sdh * wdv[e0 + 1] + cv[e0 + 1];
    o2 += sdh * wdv[e0 + 2] + cv[e0 + 2];
    float* orow = O + (size_t)bn * DIM;
    orow[e0] = o0; orow[e0 + 1] = o1; orow[e0 + 2] = o2;
}

// ---------------------------------------------------------------------------
// Kernel 5: LayerNorm + SiLU per row of 768.
// ---------------------------------------------------------------------------
__global__ __launch_bounds__(256) void ln_silu_k(
    const float* __restrict__ Z, const float* __restrict__ g,
    const float* __restrict__ bta, float* __restrict__ out)
{
    int bn = blockIdx.x, tid = threadIdx.x;
    const float* z = Z + (size_t)bn * DIM;
    int e0 = tid * 3;
    float x0 = z[e0], x1 = z[e0 + 1], x2 = z[e0 + 2];
    float s = x0 + x1 + x2;
    float ss = x0 * x0 + x1 * x1 + x2 * x2;
    __shared__ float red[4][2];
#pragma unroll
    for (int off = 32; off; off >>= 1) {
        s  += __shfl_xor(s, off);
        ss += __shfl_xor(ss, off);
    }
    int w = tid >> 6;
    if ((tid & 63) == 0) { red[w][0] = s; red[w][1] = ss; }
    __syncthreads();
    s  = red[0][0] + red[1][0] + red[2][0] + red[3][0];
    ss = red[0][1] + red[1][1] + red[2][1] + red[3][1];
    float mean = s * (1.0f / DIM);
    float var  = ss * (1.0f / DIM) - mean * mean;
    float rstd = rsqrtf(var + 1e-5f);
    float* orow = out + (size_t)bn * DIM;
#pragma unroll
    for (int i = 0; i < 3; ++i) {
        int e = e0 + i;
        float x = (i == 0) ? x0 : (i == 1) ? x1 : x2;
        float y = (x - mean) * rstd * g[e] + bta[e];
        orow[e] = y / (1.0f + __expf(-y));
    }
}

// ---------------------------------------------------------------------------
extern "C" void kernel_launch(void* const* d_in, const int* in_sizes, int n_in,
                              void* d_out, int out_size, void* d_ws, size_t ws_size,
                              hipStream_t stream)
{
    const float* features = (const float*)d_in[0];
    const float* pts      = (const float*)d_in[1];
    const float* Wd       = (const float*)d_in[2];
    const float* bd       = (const float*)d_in[3];
    const float* Wq       = (const float*)d_in[4];
    const float* bq       = (const float*)d_in[5];
    const float* Wk       = (const float*)d_in[6];
    const float* bk       = (const float*)d_in[7];
    const float* Wv       = (const float*)d_in[8];
    const float* bv       = (const float*)d_in[9];
    const float* Wo       = (const float*)d_in[10];
    const float* bo       = (const float*)d_in[11];
    const float* We       = (const float*)d_in[12];
    const float* be       = (const float*)d_in[13];
    const float* g_ln     = (const float*)d_in[14];
    const float* b_ln     = (const float*)d_in[15];

    float* ws = (float*)d_ws;
    const size_t MAT = (size_t)MROWS * DIM;    // 786432
    float* FQ    = ws;
    float* FK    = ws + MAT;
    float* FV    = ws + 2 * MAT;
    float* O     = ws + 3 * MAT;
    int*   idxb  = (int*)(ws + 4 * MAT);
    float* distb = ws + 4 * MAT + MROWS * KNN;
    float* wdk   = ws + 4 * MAT + 2 * MROWS * KNN;
    float* ck    = wdk + DIM;
    float* wdv   = ck + DIM;
    float* cv    = wdv + DIM;
    float* ATT   = FQ;   // FQ dead after attention
    float* Z     = FK;   // FK dead after attention

    prep_vecs_k<<<3, 256, 0, stream>>>(Wd, bd, Wk, bk, Wv, bv, wdk, ck, wdv, cv);
    topk_k<<<MROWS, 256, 0, stream>>>(pts, idxb, distb);
    // FQ = F@Wq + bq ; FK = F@Wk ; FV = F@Wv  (bk/bv folded into ck/cv)
    gemm64_k<<<dim3(DIM / 64, MROWS / 64, 3), 256, 0, stream>>>(
        features, Wq, Wk, Wv, bq, nullptr, nullptr, FQ, FK, FV, MROWS, DIM, DIM, 0);
    attn_k<<<MROWS, 256, 0, stream>>>(FQ, FK, FV, idxb, distb, wdk, ck, wdv, cv, O);
    // attended = O@Wo + bo
    gemm64_k<<<dim3(DIM / 64, MROWS / 64, 1), 256, 0, stream>>>(
        O, Wo, nullptr, nullptr, bo, nullptr, nullptr, ATT, nullptr, nullptr, MROWS, DIM, DIM, 0);
    // Z = F@We_top + be ; Z += ATT@We_bot
    gemm64_k<<<dim3(DIM / 64, MROWS / 64, 1), 256, 0, stream>>>(
        features, We, nullptr, nullptr, be, nullptr, nullptr, Z, nullptr, nullptr, MROWS, DIM, DIM, 0);
    gemm64_k<<<dim3(DIM / 64, MROWS / 64, 1), 256, 0, stream>>>(
        ATT, We + (size_t)DIM * DIM, nullptr, nullptr, nullptr, nullptr, nullptr,
        Z, nullptr, nullptr, MROWS, DIM, DIM, 1);
    ln_silu_k<<<MROWS, 256, 0, stream>>>(Z, g_ln, b_ln, (float*)d_out);
}

// Round 2
// 182.372 us; speedup vs baseline: 1.6575x; 1.6575x over previous
//
#include <hip/hip_runtime.h>
#include <math.h>

#define NPTS 512
#define DIM  768
#define KNN  64
#define NH   8
#define HDIM 96
#define MROWS 1024   // B*NP

typedef unsigned short u16;
typedef __attribute__((ext_vector_type(8))) short short8;
typedef __attribute__((ext_vector_type(4))) float f32x4;

__device__ __forceinline__ u16 f2bf(float f) {
    unsigned u = __float_as_uint(f);
    unsigned r = (u + 0x7fffu + ((u >> 16) & 1u)) >> 16;   // round-to-nearest-even
    return (u16)r;
}

// ---------------------------------------------------------------------------
// Kernel 1: fold distance-encoder through Wk/Wv (fp32, tiny):
//   wdk = Wd @ Wk, ck = bd @ Wk + bk, wdv = Wd @ Wv, cv = bd @ Wv + bv
// ---------------------------------------------------------------------------
__global__ __launch_bounds__(256) void prep_vecs_k(
    const float* __restrict__ Wd, const float* __restrict__ bd,
    const float* __restrict__ Wk, const float* __restrict__ bk,
    const float* __restrict__ Wv, const float* __restrict__ bv,
    float* __restrict__ wdk, float* __restrict__ ck,
    float* __restrict__ wdv, float* __restrict__ cv)
{
    int n = blockIdx.x * 256 + threadIdx.x;
    if (n >= DIM) return;
    float a = 0.f, b = 0.f, c = 0.f, d = 0.f;
    for (int k = 0; k < DIM; ++k) {
        float wd = Wd[k], bdk = bd[k];
        float wkv = Wk[k * DIM + n], wvv = Wv[k * DIM + n];
        a += wd * wkv; b += bdk * wkv;
        c += wd * wvv; d += bdk * wvv;
    }
    wdk[n] = a; ck[n] = b + bk[n];
    wdv[n] = c; cv[n] = d + bv[n];
}

// ---------------------------------------------------------------------------
// Kernel 2: per-point pairwise distance + top-64 (bitonic sort of 512 keys).
// ---------------------------------------------------------------------------
__global__ __launch_bounds__(256) void topk_k(
    const float* __restrict__ pts, int* __restrict__ idxb, float* __restrict__ distb)
{
    int bn = blockIdx.x;            // 0..1023
    int b  = bn >> 9;
    int n  = bn & (NPTS - 1);
    __shared__ float P[NPTS * 3];
    __shared__ unsigned long long keys[NPTS];
    const float* pb = pts + (size_t)b * NPTS * 3;
    for (int i = threadIdx.x; i < NPTS * 3; i += 256) P[i] = pb[i];
    __syncthreads();
    float xn = P[n * 3], yn = P[n * 3 + 1], zn = P[n * 3 + 2];
    float sqn = xn * xn + yn * yn + zn * zn;
    for (int m = threadIdx.x; m < NPTS; m += 256) {
        float xm = P[m * 3], ym = P[m * 3 + 1], zm = P[m * 3 + 2];
        float sqm = xm * xm + ym * ym + zm * zm;
        float d2 = sqn + sqm - 2.0f * (xn * xm + yn * ym + zn * zm);
        float dist = sqrtf(fmaxf(d2, 0.0f));
        keys[m] = (((unsigned long long)__float_as_uint(dist)) << 32) | (unsigned)m;
    }
    __syncthreads();
    for (int k = 2; k <= NPTS; k <<= 1) {
        for (int j = k >> 1; j > 0; j >>= 1) {
            for (int i = threadIdx.x; i < NPTS; i += 256) {
                int ixj = i ^ j;
                if (ixj > i) {
                    bool asc = ((i & k) == 0);
                    unsigned long long a = keys[i], bb = keys[ixj];
                    if ((a > bb) == asc) { keys[i] = bb; keys[ixj] = a; }
                }
            }
            __syncthreads();
        }
    }
    if (threadIdx.x < KNN) {
        unsigned long long kk = keys[threadIdx.x];
        idxb[(size_t)bn * KNN + threadIdx.x]  = (int)(kk & 0xffffffffu);
        distb[(size_t)bn * KNN + threadIdx.x] = __uint_as_float((unsigned)(kk >> 32));
    }
}

// ---------------------------------------------------------------------------
// Kernel 3a: fp32 -> bf16 elementwise (features)
// ---------------------------------------------------------------------------
__global__ __launch_bounds__(256) void convF_k(const float* __restrict__ S, u16* __restrict__ D)
{
    int i = (blockIdx.x * 256 + threadIdx.x) * 4;
    float4 v = *(const float4*)&S[i];
    uint2 o;
    o.x = (unsigned)f2bf(v.x) | ((unsigned)f2bf(v.y) << 16);
    o.y = (unsigned)f2bf(v.z) | ((unsigned)f2bf(v.w) << 16);
    *(uint2*)&D[i] = o;
}

// ---------------------------------------------------------------------------
// Kernel 3b: transpose-convert W [768][768] fp32 -> WT [768][768] bf16.
// Up to 3 matrices selected by blockIdx.z.
// ---------------------------------------------------------------------------
__global__ __launch_bounds__(256) void convT_k(
    const float* __restrict__ S0, const float* __restrict__ S1, const float* __restrict__ S2,
    u16* __restrict__ D0, u16* __restrict__ D1, u16* __restrict__ D2)
{
    const float* S = (blockIdx.z == 0) ? S0 : (blockIdx.z == 1) ? S1 : S2;
    u16*         D = (blockIdx.z == 0) ? D0 : (blockIdx.z == 1) ? D1 : D2;
    __shared__ float T[64][65];
    int r0 = blockIdx.y * 64, c0 = blockIdx.x * 64;
#pragma unroll
    for (int i = 0; i < 16; ++i) {
        int lin = threadIdx.x + i * 256;
        int r = lin >> 6, c = lin & 63;
        T[r][c] = S[(size_t)(r0 + r) * DIM + c0 + c];
    }
    __syncthreads();
#pragma unroll
    for (int i = 0; i < 16; ++i) {
        int lin = threadIdx.x + i * 256;
        int c = lin >> 6, r = lin & 63;
        D[(size_t)(c0 + c) * DIM + r0 + r] = f2bf(T[r][c]);
    }
}

// ---------------------------------------------------------------------------
// Kernel 4: bf16 MFMA GEMM, 64x64 tile, 4 waves (32x32 each, 2x2 frags),
// BK=64, K=768 per A/B pair. B is pre-transposed: BT[n][k].
// MODE 0: z in {0,1,2}: C{0,1,2} = A0 @ BT{0,1,2} (+bias{z}), fp32 out
// MODE 1: Cb = bf16(A0 @ BT0 + bias0)
// MODE 2: C0 = A0 @ BT0 + A1 @ BT1 + bias0, fp32 out
// ---------------------------------------------------------------------------
template<int MODE>
__global__ __launch_bounds__(256) void gemm_mfma_k(
    const u16* __restrict__ A0, const u16* __restrict__ A1,
    const u16* __restrict__ B0, const u16* __restrict__ B1, const u16* __restrict__ B2,
    const float* __restrict__ bias0, const float* __restrict__ bias1, const float* __restrict__ bias2,
    float* __restrict__ C0, float* __restrict__ C1, float* __restrict__ C2,
    u16* __restrict__ Cb)
{
    const u16*   BT   = B0;
    const float* bias = bias0;
    float*       Cf   = C0;
    if (MODE == 0) {
        if (blockIdx.z == 1)      { BT = B1; bias = bias1; Cf = C1; }
        else if (blockIdx.z == 2) { BT = B2; bias = bias2; Cf = C2; }
    }

    __shared__ short As[64][72];   // 72-short stride: 16B-aligned, ~2-way banks
    __shared__ short Bs[64][72];

    int tid  = threadIdx.x;
    int wave = tid >> 6, lane = tid & 63;
    int wr = (wave >> 1) * 32, wc = (wave & 1) * 32;
    int l15 = lane & 15, kg = lane >> 4;
    int brow = blockIdx.y * 64, bcol = blockIdx.x * 64;

    f32x4 acc[2][2] = {};

    int srow = tid >> 3;            // 0..31
    int scol = (tid & 7) * 8;       // 0,8,..,56

    const int npair = (MODE == 2) ? 2 : 1;
    for (int p = 0; p < npair; ++p) {
        const u16* Ap = (MODE == 2 && p == 1) ? A1 : A0;
        const u16* Bp = (MODE == 2 && p == 1) ? B1 : BT;
        for (int k0 = 0; k0 < DIM; k0 += 64) {
#pragma unroll
            for (int s = 0; s < 2; ++s) {
                int r = srow + s * 32;
                *(short8*)&As[r][scol] = *(const short8*)&Ap[(size_t)(brow + r) * DIM + k0 + scol];
                *(short8*)&Bs[r][scol] = *(const short8*)&Bp[(size_t)(bcol + r) * DIM + k0 + scol];
            }
            __syncthreads();
#pragma unroll
            for (int kk = 0; kk < 2; ++kk) {
                short8 a0 = *(const short8*)&As[wr + l15][kk * 32 + kg * 8];
                short8 a1 = *(const short8*)&As[wr + 16 + l15][kk * 32 + kg * 8];
                short8 b0 = *(const short8*)&Bs[wc + l15][kk * 32 + kg * 8];
                short8 b1 = *(const short8*)&Bs[wc + 16 + l15][kk * 32 + kg * 8];
                acc[0][0] = __builtin_amdgcn_mfma_f32_16x16x32_bf16(a0, b0, acc[0][0], 0, 0, 0);
                acc[0][1] = __builtin_amdgcn_mfma_f32_16x16x32_bf16(a0, b1, acc[0][1], 0, 0, 0);
                acc[1][0] = __builtin_amdgcn_mfma_f32_16x16x32_bf16(a1, b0, acc[1][0], 0, 0, 0);
                acc[1][1] = __builtin_amdgcn_mfma_f32_16x16x32_bf16(a1, b1, acc[1][1], 0, 0, 0);
            }
            __syncthreads();
        }
    }

    // epilogue: D layout col = lane&15, row = (lane>>4)*4 + j   [m89/m91 verified]
#pragma unroll
    for (int m = 0; m < 2; ++m) {
#pragma unroll
        for (int n = 0; n < 2; ++n) {
            int col = bcol + wc + n * 16 + l15;
            float bv = bias ? bias[col] : 0.f;
#pragma unroll
            for (int j = 0; j < 4; ++j) {
                int row = brow + wr + m * 16 + kg * 4 + j;
                float v = acc[m][n][j] + bv;
                if (MODE == 1) Cb[(size_t)row * DIM + col] = f2bf(v);
                else           Cf[(size_t)row * DIM + col] = v;
            }
        }
    }
}

// ---------------------------------------------------------------------------
// Kernel 5: fused neighbor attention (fp32 math, bf16 output).
//   score_j = (q . FK[idx_j] + dist_j*(q.wdk) + (q.ck)) / sqrt(96)
//   o = sum_j attn_j*FV[idx_j] + (sum_j attn_j*dist_j)*wdv + cv
// ---------------------------------------------------------------------------
__global__ __launch_bounds__(256) void attn_k(
    const float* __restrict__ FQ, const float* __restrict__ FK, const float* __restrict__ FV,
    const int* __restrict__ idxb, const float* __restrict__ distb,
    const float* __restrict__ wdk, const float* __restrict__ ck,
    const float* __restrict__ wdv, const float* __restrict__ cv,
    u16* __restrict__ O)
{
    int bn = blockIdx.x;
    int b  = bn >> 9;
    int tid = threadIdx.x;
    int h = tid >> 5;
    int lane32 = tid & 31;

    __shared__ int   s_idx[KNN];
    __shared__ float s_dist[KNN];
    __shared__ float s_sc[NH][KNN];
    __shared__ float s_att[NH][KNN];
    __shared__ float s_qh[NH][2];
    __shared__ float s_sd[NH];

    if (tid < KNN) {
        s_idx[tid]  = idxb[(size_t)bn * KNN + tid];
        s_dist[tid] = distb[(size_t)bn * KNN + tid];
    }

    int e0 = tid * 3;
    const float* qrow = FQ + (size_t)bn * DIM;
    float q0 = qrow[e0], q1 = qrow[e0 + 1], q2 = qrow[e0 + 2];

    float pw = q0 * wdk[e0] + q1 * wdk[e0 + 1] + q2 * wdk[e0 + 2];
    float pc = q0 * ck[e0]  + q1 * ck[e0 + 1]  + q2 * ck[e0 + 2];
#pragma unroll
    for (int off = 16; off; off >>= 1) {
        pw += __shfl_xor(pw, off);
        pc += __shfl_xor(pc, off);
    }
    if (lane32 == 0) { s_qh[h][0] = pw; s_qh[h][1] = pc; }
    __syncthreads();

    float qwdk = s_qh[h][0], qck = s_qh[h][1];
    const float invs = 0.10206207261596575f;  // 1/sqrt(96)
    int base = b * NPTS;

    for (int j = 0; j < KNN; ++j) {
        const float* kr = FK + (size_t)(base + s_idx[j]) * DIM;
        float p = q0 * kr[e0] + q1 * kr[e0 + 1] + q2 * kr[e0 + 2];
#pragma unroll
        for (int off = 16; off; off >>= 1) p += __shfl_xor(p, off);
        if (lane32 == 0) s_sc[h][j] = (p + s_dist[j] * qwdk + qck) * invs;
    }
    __syncthreads();

    float s0 = s_sc[h][lane32], s1 = s_sc[h][lane32 + 32];
    float mx = fmaxf(s0, s1);
#pragma unroll
    for (int off = 16; off; off >>= 1) mx = fmaxf(mx, __shfl_xor(mx, off));
    float ev0 = __expf(s0 - mx), ev1 = __expf(s1 - mx);
    float sum = ev0 + ev1;
#pragma unroll
    for (int off = 16; off; off >>= 1) sum += __shfl_xor(sum, off);
    float rs = 1.0f / sum;
    float a0 = ev0 * rs, a1 = ev1 * rs;
    s_att[h][lane32] = a0; s_att[h][lane32 + 32] = a1;
    float sd = a0 * s_dist[lane32] + a1 * s_dist[lane32 + 32];
#pragma unroll
    for (int off = 16; off; off >>= 1) sd += __shfl_xor(sd, off);
    if (lane32 == 0) s_sd[h] = sd;
    __syncthreads();

    float o0 = 0.f, o1 = 0.f, o2 = 0.f;
    for (int j = 0; j < KNN; ++j) {
        const float* vr = FV + (size_t)(base + s_idx[j]) * DIM;
        float a = s_att[h][j];
        o0 = fmaf(a, vr[e0], o0);
        o1 = fmaf(a, vr[e0 + 1], o1);
        o2 = fmaf(a, vr[e0 + 2], o2);
    }
    float sdh = s_sd[h];
    o0 += sdh * wdv[e0]     + cv[e0];
    o1 += sdh * wdv[e0 + 1] + cv[e0 + 1];
    o2 += sdh * wdv[e0 + 2] + cv[e0 + 2];
    u16* orow = O + (size_t)bn * DIM;
    orow[e0] = f2bf(o0); orow[e0 + 1] = f2bf(o1); orow[e0 + 2] = f2bf(o2);
}

// ---------------------------------------------------------------------------
// Kernel 6: LayerNorm + SiLU per row of 768.
// ---------------------------------------------------------------------------
__global__ __launch_bounds__(256) void ln_silu_k(
    const float* __restrict__ Z, const float* __restrict__ g,
    const float* __restrict__ bta, float* __restrict__ out)
{
    int bn = blockIdx.x, tid = threadIdx.x;
    const float* z = Z + (size_t)bn * DIM;
    int e0 = tid * 3;
    float x0 = z[e0], x1 = z[e0 + 1], x2 = z[e0 + 2];
    float s = x0 + x1 + x2;
    float ss = x0 * x0 + x1 * x1 + x2 * x2;
    __shared__ float red[4][2];
#pragma unroll
    for (int off = 32; off; off >>= 1) {
        s  += __shfl_xor(s, off);
        ss += __shfl_xor(ss, off);
    }
    int w = tid >> 6;
    if ((tid & 63) == 0) { red[w][0] = s; red[w][1] = ss; }
    __syncthreads();
    s  = red[0][0] + red[1][0] + red[2][0] + red[3][0];
    ss = red[0][1] + red[1][1] + red[2][1] + red[3][1];
    float mean = s * (1.0f / DIM);
    float var  = ss * (1.0f / DIM) - mean * mean;
    float rstd = rsqrtf(var + 1e-5f);
    float* orow = out + (size_t)bn * DIM;
#pragma unroll
    for (int i = 0; i < 3; ++i) {
        int e = e0 + i;
        float x = (i == 0) ? x0 : (i == 1) ? x1 : x2;
        float y = (x - mean) * rstd * g[e] + bta[e];
        orow[e] = y / (1.0f + __expf(-y));
    }
}

// ---------------------------------------------------------------------------
extern "C" void kernel_launch(void* const* d_in, const int* in_sizes, int n_in,
                              void* d_out, int out_size, void* d_ws, size_t ws_size,
                              hipStream_t stream)
{
    const float* features = (const float*)d_in[0];
    const float* pts      = (const float*)d_in[1];
    const float* Wd       = (const float*)d_in[2];
    const float* bd       = (const float*)d_in[3];
    const float* Wq       = (const float*)d_in[4];
    const float* bq       = (const float*)d_in[5];
    const float* Wk       = (const float*)d_in[6];
    const float* bk       = (const float*)d_in[7];
    const float* Wv       = (const float*)d_in[8];
    const float* bv       = (const float*)d_in[9];
    const float* Wo       = (const float*)d_in[10];
    const float* bo       = (const float*)d_in[11];
    const float* We       = (const float*)d_in[12];
    const float* be       = (const float*)d_in[13];
    const float* g_ln     = (const float*)d_in[14];
    const float* b_ln     = (const float*)d_in[15];

    const size_t MAT = (size_t)MROWS * DIM;    // 786432
    const size_t WSQ = (size_t)DIM * DIM;      // 589824

    float* ws = (float*)d_ws;
    float* FQ    = ws;                 // -> reused as Z after attention
    float* FK    = ws + MAT;           // -> reused as ATT_bf (u16) after attention
    float* FV    = ws + 2 * MAT;
    u16*   Fb    = (u16*)(ws + 3 * MAT);
    u16*   Ob    = Fb + MAT;
    u16*   W3    = Ob + MAT;           // 3 x [768][768] bf16, staged reuse
    char*  tail  = (char*)(W3 + 3 * WSQ);
    int*   idxb  = (int*)tail;
    float* distb = (float*)(tail + MROWS * KNN * 4);
    float* wdk   = (float*)(tail + 2 * MROWS * KNN * 4);
    float* ck    = wdk + DIM;
    float* wdv   = ck + DIM;
    float* cv    = wdv + DIM;
    float* Z     = FQ;
    u16*   ATTb  = (u16*)FK;

    prep_vecs_k<<<3, 256, 0, stream>>>(Wd, bd, Wk, bk, Wv, bv, wdk, ck, wdv, cv);
    topk_k<<<MROWS, 256, 0, stream>>>(pts, idxb, distb);
    convF_k<<<(int)(MAT / 1024), 256, 0, stream>>>(features, Fb);
    // WqT, WkT, WvT -> W3
    convT_k<<<dim3(12, 12, 3), 256, 0, stream>>>(Wq, Wk, Wv, W3, W3 + WSQ, W3 + 2 * WSQ);
    // FQ = F@Wq + bq ; FK = F@Wk ; FV = F@Wv (bk/bv folded into ck/cv)
    gemm_mfma_k<0><<<dim3(12, 16, 3), 256, 0, stream>>>(
        Fb, nullptr, W3, W3 + WSQ, W3 + 2 * WSQ, bq, nullptr, nullptr, FQ, FK, FV, nullptr);
    attn_k<<<MROWS, 256, 0, stream>>>(FQ, FK, FV, idxb, distb, wdk, ck, wdv, cv, Ob);
    // WoT -> W3[0] (WqT dead)
    convT_k<<<dim3(12, 12, 1), 256, 0, stream>>>(Wo, nullptr, nullptr, W3, nullptr, nullptr);
    // ATTb = bf16(O @ Wo + bo)
    gemm_mfma_k<1><<<dim3(12, 16, 1), 256, 0, stream>>>(
        Ob, nullptr, W3, nullptr, nullptr, bo, nullptr, nullptr, nullptr, nullptr, nullptr, ATTb);
    // WeT_top -> W3[0], WeT_bot -> W3[1]
    convT_k<<<dim3(12, 12, 2), 256, 0, stream>>>(We, We + WSQ, nullptr, W3, W3 + WSQ, nullptr);
    // Z = F@We_top + ATT@We_bot + be
    gemm_mfma_k<2><<<dim3(12, 16, 1), 256, 0, stream>>>(
        Fb, ATTb, W3, W3 + WSQ, nullptr, be, nullptr, nullptr, Z, nullptr, nullptr, nullptr);
    ln_silu_k<<<MROWS, 256, 0, stream>>>(Z, g_ln, b_ln, (float*)d_out);
}

// Round 3
// 143.203 us; speedup vs baseline: 2.1109x; 1.2735x over previous
//
#include <hip/hip_runtime.h>
#include <math.h>

#define NPTS 512
#define DIM  768
#define KNN  64
#define NH   8
#define HDIM 96
#define MROWS 1024   // B*NP

typedef unsigned short u16;
typedef __attribute__((ext_vector_type(8))) short short8;
typedef __attribute__((ext_vector_type(4))) float f32x4;

__device__ __forceinline__ u16 f2bf(float f) {
    unsigned u = __float_as_uint(f);
    unsigned r = (u + 0x7fffu + ((u >> 16) & 1u)) >> 16;   // round-to-nearest-even
    return (u16)r;
}

// ---------------------------------------------------------------------------
// Kernel 1a: split-K partials for the distance-encoder fold.
// grid (3, 16): block (bx,by) covers cols [bx*256,+256), k in [by*48,+48).
// part[by][{wdk,ck,wdv,cv}][768]  (deterministic, no atomics)
// ---------------------------------------------------------------------------
__global__ __launch_bounds__(256) void prep_partial_k(
    const float* __restrict__ Wd, const float* __restrict__ bd,
    const float* __restrict__ Wk, const float* __restrict__ Wv,
    float* __restrict__ part)
{
    int col = blockIdx.x * 256 + threadIdx.x;
    int k0  = blockIdx.y * 48;
    float a = 0.f, b = 0.f, c = 0.f, d = 0.f;
#pragma unroll 4
    for (int i = 0; i < 48; ++i) {
        int k = k0 + i;
        float wd = Wd[k], bdk = bd[k];
        float wkv = Wk[(size_t)k * DIM + col];
        float wvv = Wv[(size_t)k * DIM + col];
        a = fmaf(wd, wkv, a); b = fmaf(bdk, wkv, b);
        c = fmaf(wd, wvv, c); d = fmaf(bdk, wvv, d);
    }
    float* p = part + (size_t)blockIdx.y * 4 * DIM;
    p[col] = a; p[DIM + col] = b; p[2 * DIM + col] = c; p[3 * DIM + col] = d;
}

// ---------------------------------------------------------------------------
// Kernel 1b: reduce the 16 partials, add bk/bv.
// ---------------------------------------------------------------------------
__global__ __launch_bounds__(256) void prep_reduce_k(
    const float* __restrict__ part,
    const float* __restrict__ bk, const float* __restrict__ bv,
    float* __restrict__ wdk, float* __restrict__ ck,
    float* __restrict__ wdv, float* __restrict__ cv)
{
    int col = blockIdx.x * 256 + threadIdx.x;
    float a = 0.f, b = 0.f, c = 0.f, d = 0.f;
#pragma unroll
    for (int j = 0; j < 16; ++j) {
        const float* p = part + (size_t)j * 4 * DIM;
        a += p[col]; b += p[DIM + col]; c += p[2 * DIM + col]; d += p[3 * DIM + col];
    }
    wdk[col] = a; ck[col] = b + bk[col];
    wdv[col] = c; cv[col] = d + bv[col];
}

// ---------------------------------------------------------------------------
// Kernel 2: per-point pairwise distance + top-64 (bitonic sort of 512 keys).
// ---------------------------------------------------------------------------
__global__ __launch_bounds__(256) void topk_k(
    const float* __restrict__ pts, int* __restrict__ idxb, float* __restrict__ distb)
{
    int bn = blockIdx.x;            // 0..1023
    int b  = bn >> 9;
    int n  = bn & (NPTS - 1);
    __shared__ float P[NPTS * 3];
    __shared__ unsigned long long keys[NPTS];
    const float* pb = pts + (size_t)b * NPTS * 3;
    for (int i = threadIdx.x; i < NPTS * 3; i += 256) P[i] = pb[i];
    __syncthreads();
    float xn = P[n * 3], yn = P[n * 3 + 1], zn = P[n * 3 + 2];
    float sqn = xn * xn + yn * yn + zn * zn;
    for (int m = threadIdx.x; m < NPTS; m += 256) {
        float xm = P[m * 3], ym = P[m * 3 + 1], zm = P[m * 3 + 2];
        float sqm = xm * xm + ym * ym + zm * zm;
        float d2 = sqn + sqm - 2.0f * (xn * xm + yn * ym + zn * zm);
        float dist = sqrtf(fmaxf(d2, 0.0f));
        keys[m] = (((unsigned long long)__float_as_uint(dist)) << 32) | (unsigned)m;
    }
    __syncthreads();
    for (int k = 2; k <= NPTS; k <<= 1) {
        for (int j = k >> 1; j > 0; j >>= 1) {
            for (int i = threadIdx.x; i < NPTS; i += 256) {
                int ixj = i ^ j;
                if (ixj > i) {
                    bool asc = ((i & k) == 0);
                    unsigned long long a = keys[i], bb = keys[ixj];
                    if ((a > bb) == asc) { keys[i] = bb; keys[ixj] = a; }
                }
            }
            __syncthreads();
        }
    }
    if (threadIdx.x < KNN) {
        unsigned long long kk = keys[threadIdx.x];
        idxb[(size_t)bn * KNN + threadIdx.x]  = (int)(kk & 0xffffffffu);
        distb[(size_t)bn * KNN + threadIdx.x] = __uint_as_float((unsigned)(kk >> 32));
    }
}

// ---------------------------------------------------------------------------
// Kernel 3a: fp32 -> bf16 elementwise (features)
// ---------------------------------------------------------------------------
__global__ __launch_bounds__(256) void convF_k(const float* __restrict__ S, u16* __restrict__ D)
{
    int i = (blockIdx.x * 256 + threadIdx.x) * 4;
    float4 v = *(const float4*)&S[i];
    uint2 o;
    o.x = (unsigned)f2bf(v.x) | ((unsigned)f2bf(v.y) << 16);
    o.y = (unsigned)f2bf(v.z) | ((unsigned)f2bf(v.w) << 16);
    *(uint2*)&D[i] = o;
}

// ---------------------------------------------------------------------------
// Kernel 3b: transpose-convert W [768][768] fp32 -> WT [768][768] bf16.
// Up to 3 matrices selected by blockIdx.z.
// ---------------------------------------------------------------------------
__global__ __launch_bounds__(256) void convT_k(
    const float* __restrict__ S0, const float* __restrict__ S1, const float* __restrict__ S2,
    u16* __restrict__ D0, u16* __restrict__ D1, u16* __restrict__ D2)
{
    const float* S = (blockIdx.z == 0) ? S0 : (blockIdx.z == 1) ? S1 : S2;
    u16*         D = (blockIdx.z == 0) ? D0 : (blockIdx.z == 1) ? D1 : D2;
    __shared__ float T[64][65];
    int r0 = blockIdx.y * 64, c0 = blockIdx.x * 64;
#pragma unroll
    for (int i = 0; i < 16; ++i) {
        int lin = threadIdx.x + i * 256;
        int r = lin >> 6, c = lin & 63;
        T[r][c] = S[(size_t)(r0 + r) * DIM + c0 + c];
    }
    __syncthreads();
#pragma unroll
    for (int i = 0; i < 16; ++i) {
        int lin = threadIdx.x + i * 256;
        int c = lin >> 6, r = lin & 63;
        D[(size_t)(c0 + c) * DIM + r0 + r] = f2bf(T[r][c]);
    }
}

// ---------------------------------------------------------------------------
// Kernel 4: bf16 MFMA GEMM, 64x64 tile, 4 waves (32x32 each, 2x2 frags),
// BK=64, K=768 per A/B pair. B is pre-transposed: BT[n][k].
// MODE 0: z in {0,1,2}: C{0,1,2} = A0 @ BT{0,1,2} (+bias{z}), fp32 out
// MODE 1: Cb = bf16(A0 @ BT0 + bias0)
// MODE 2: C0 = A0 @ BT0 + A1 @ BT1 + bias0, fp32 out
// ---------------------------------------------------------------------------
template<int MODE>
__global__ __launch_bounds__(256) void gemm_mfma_k(
    const u16* __restrict__ A0, const u16* __restrict__ A1,
    const u16* __restrict__ B0, const u16* __restrict__ B1, const u16* __restrict__ B2,
    const float* __restrict__ bias0, const float* __restrict__ bias1, const float* __restrict__ bias2,
    float* __restrict__ C0, float* __restrict__ C1, float* __restrict__ C2,
    u16* __restrict__ Cb)
{
    const u16*   BT   = B0;
    const float* bias = bias0;
    float*       Cf   = C0;
    if (MODE == 0) {
        if (blockIdx.z == 1)      { BT = B1; bias = bias1; Cf = C1; }
        else if (blockIdx.z == 2) { BT = B2; bias = bias2; Cf = C2; }
    }

    __shared__ short As[64][72];   // 72-short stride: 16B-aligned, ~2-way banks
    __shared__ short Bs[64][72];

    int tid  = threadIdx.x;
    int wave = tid >> 6, lane = tid & 63;
    int wr = (wave >> 1) * 32, wc = (wave & 1) * 32;
    int l15 = lane & 15, kg = lane >> 4;
    int brow = blockIdx.y * 64, bcol = blockIdx.x * 64;

    f32x4 acc[2][2] = {};

    int srow = tid >> 3;            // 0..31
    int scol = (tid & 7) * 8;       // 0,8,..,56

    const int npair = (MODE == 2) ? 2 : 1;
    for (int p = 0; p < npair; ++p) {
        const u16* Ap = (MODE == 2 && p == 1) ? A1 : A0;
        const u16* Bp = (MODE == 2 && p == 1) ? B1 : BT;
        for (int k0 = 0; k0 < DIM; k0 += 64) {
#pragma unroll
            for (int s = 0; s < 2; ++s) {
                int r = srow + s * 32;
                *(short8*)&As[r][scol] = *(const short8*)&Ap[(size_t)(brow + r) * DIM + k0 + scol];
                *(short8*)&Bs[r][scol] = *(const short8*)&Bp[(size_t)(bcol + r) * DIM + k0 + scol];
            }
            __syncthreads();
#pragma unroll
            for (int kk = 0; kk < 2; ++kk) {
                short8 a0 = *(const short8*)&As[wr + l15][kk * 32 + kg * 8];
                short8 a1 = *(const short8*)&As[wr + 16 + l15][kk * 32 + kg * 8];
                short8 b0 = *(const short8*)&Bs[wc + l15][kk * 32 + kg * 8];
                short8 b1 = *(const short8*)&Bs[wc + 16 + l15][kk * 32 + kg * 8];
                acc[0][0] = __builtin_amdgcn_mfma_f32_16x16x32_bf16(a0, b0, acc[0][0], 0, 0, 0);
                acc[0][1] = __builtin_amdgcn_mfma_f32_16x16x32_bf16(a0, b1, acc[0][1], 0, 0, 0);
                acc[1][0] = __builtin_amdgcn_mfma_f32_16x16x32_bf16(a1, b0, acc[1][0], 0, 0, 0);
                acc[1][1] = __builtin_amdgcn_mfma_f32_16x16x32_bf16(a1, b1, acc[1][1], 0, 0, 0);
            }
            __syncthreads();
        }
    }

    // epilogue: D layout col = lane&15, row = (lane>>4)*4 + j   [m89/m91 verified]
#pragma unroll
    for (int m = 0; m < 2; ++m) {
#pragma unroll
        for (int n = 0; n < 2; ++n) {
            int col = bcol + wc + n * 16 + l15;
            float bv = bias ? bias[col] : 0.f;
#pragma unroll
            for (int j = 0; j < 4; ++j) {
                int row = brow + wr + m * 16 + kg * 4 + j;
                float v = acc[m][n][j] + bv;
                if (MODE == 1) Cb[(size_t)row * DIM + col] = f2bf(v);
                else           Cf[(size_t)row * DIM + col] = v;
            }
        }
    }
}

// ---------------------------------------------------------------------------
// Kernel 5: fused neighbor attention (fp32 math, bf16 output).
//   score_j = (q . FK[idx_j] + dist_j*(q.wdk) + (q.ck)) / sqrt(96)
//   o = sum_j attn_j*FV[idx_j] + (sum_j attn_j*dist_j)*wdv + cv
// ---------------------------------------------------------------------------
__global__ __launch_bounds__(256) void attn_k(
    const float* __restrict__ FQ, const float* __restrict__ FK, const float* __restrict__ FV,
    const int* __restrict__ idxb, const float* __restrict__ distb,
    const float* __restrict__ wdk, const float* __restrict__ ck,
    const float* __restrict__ wdv, const float* __restrict__ cv,
    u16* __restrict__ O)
{
    int bn = blockIdx.x;
    int b  = bn >> 9;
    int tid = threadIdx.x;
    int h = tid >> 5;
    int lane32 = tid & 31;

    __shared__ int   s_idx[KNN];
    __shared__ float s_dist[KNN];
    __shared__ float s_sc[NH][KNN];
    __shared__ float s_att[NH][KNN];
    __shared__ float s_qh[NH][2];
    __shared__ float s_sd[NH];

    if (tid < KNN) {
        s_idx[tid]  = idxb[(size_t)bn * KNN + tid];
        s_dist[tid] = distb[(size_t)bn * KNN + tid];
    }

    int e0 = tid * 3;
    const float* qrow = FQ + (size_t)bn * DIM;
    float q0 = qrow[e0], q1 = qrow[e0 + 1], q2 = qrow[e0 + 2];

    float pw = q0 * wdk[e0] + q1 * wdk[e0 + 1] + q2 * wdk[e0 + 2];
    float pc = q0 * ck[e0]  + q1 * ck[e0 + 1]  + q2 * ck[e0 + 2];
#pragma unroll
    for (int off = 16; off; off >>= 1) {
        pw += __shfl_xor(pw, off);
        pc += __shfl_xor(pc, off);
    }
    if (lane32 == 0) { s_qh[h][0] = pw; s_qh[h][1] = pc; }
    __syncthreads();

    float qwdk = s_qh[h][0], qck = s_qh[h][1];
    const float invs = 0.10206207261596575f;  // 1/sqrt(96)
    int base = b * NPTS;

    for (int j = 0; j < KNN; ++j) {
        const float* kr = FK + (size_t)(base + s_idx[j]) * DIM;
        float p = q0 * kr[e0] + q1 * kr[e0 + 1] + q2 * kr[e0 + 2];
#pragma unroll
        for (int off = 16; off; off >>= 1) p += __shfl_xor(p, off);
        if (lane32 == 0) s_sc[h][j] = (p + s_dist[j] * qwdk + qck) * invs;
    }
    __syncthreads();

    float s0 = s_sc[h][lane32], s1 = s_sc[h][lane32 + 32];
    float mx = fmaxf(s0, s1);
#pragma unroll
    for (int off = 16; off; off >>= 1) mx = fmaxf(mx, __shfl_xor(mx, off));
    float ev0 = __expf(s0 - mx), ev1 = __expf(s1 - mx);
    float sum = ev0 + ev1;
#pragma unroll
    for (int off = 16; off; off >>= 1) sum += __shfl_xor(sum, off);
    float rs = 1.0f / sum;
    float a0 = ev0 * rs, a1 = ev1 * rs;
    s_att[h][lane32] = a0; s_att[h][lane32 + 32] = a1;
    float sd = a0 * s_dist[lane32] + a1 * s_dist[lane32 + 32];
#pragma unroll
    for (int off = 16; off; off >>= 1) sd += __shfl_xor(sd, off);
    if (lane32 == 0) s_sd[h] = sd;
    __syncthreads();

    float o0 = 0.f, o1 = 0.f, o2 = 0.f;
    for (int j = 0; j < KNN; ++j) {
        const float* vr = FV + (size_t)(base + s_idx[j]) * DIM;
        float a = s_att[h][j];
        o0 = fmaf(a, vr[e0], o0);
        o1 = fmaf(a, vr[e0 + 1], o1);
        o2 = fmaf(a, vr[e0 + 2], o2);
    }
    float sdh = s_sd[h];
    o0 += sdh * wdv[e0]     + cv[e0];
    o1 += sdh * wdv[e0 + 1] + cv[e0 + 1];
    o2 += sdh * wdv[e0 + 2] + cv[e0 + 2];
    u16* orow = O + (size_t)bn * DIM;
    orow[e0] = f2bf(o0); orow[e0 + 1] = f2bf(o1); orow[e0 + 2] = f2bf(o2);
}

// ---------------------------------------------------------------------------
// Kernel 6: LayerNorm + SiLU per row of 768.
// ---------------------------------------------------------------------------
__global__ __launch_bounds__(256) void ln_silu_k(
    const float* __restrict__ Z, const float* __restrict__ g,
    const float* __restrict__ bta, float* __restrict__ out)
{
    int bn = blockIdx.x, tid = threadIdx.x;
    const float* z = Z + (size_t)bn * DIM;
    int e0 = tid * 3;
    float x0 = z[e0], x1 = z[e0 + 1], x2 = z[e0 + 2];
    float s = x0 + x1 + x2;
    float ss = x0 * x0 + x1 * x1 + x2 * x2;
    __shared__ float red[4][2];
#pragma unroll
    for (int off = 32; off; off >>= 1) {
        s  += __shfl_xor(s, off);
        ss += __shfl_xor(ss, off);
    }
    int w = tid >> 6;
    if ((tid & 63) == 0) { red[w][0] = s; red[w][1] = ss; }
    __syncthreads();
    s  = red[0][0] + red[1][0] + red[2][0] + red[3][0];
    ss = red[0][1] + red[1][1] + red[2][1] + red[3][1];
    float mean = s * (1.0f / DIM);
    float var  = ss * (1.0f / DIM) - mean * mean;
    float rstd = rsqrtf(var + 1e-5f);
    float* orow = out + (size_t)bn * DIM;
#pragma unroll
    for (int i = 0; i < 3; ++i) {
        int e = e0 + i;
        float x = (i == 0) ? x0 : (i == 1) ? x1 : x2;
        float y = (x - mean) * rstd * g[e] + bta[e];
        orow[e] = y / (1.0f + __expf(-y));
    }
}

// ---------------------------------------------------------------------------
extern "C" void kernel_launch(void* const* d_in, const int* in_sizes, int n_in,
                              void* d_out, int out_size, void* d_ws, size_t ws_size,
                              hipStream_t stream)
{
    const float* features = (const float*)d_in[0];
    const float* pts      = (const float*)d_in[1];
    const float* Wd       = (const float*)d_in[2];
    const float* bd       = (const float*)d_in[3];
    const float* Wq       = (const float*)d_in[4];
    const float* bq       = (const float*)d_in[5];
    const float* Wk       = (const float*)d_in[6];
    const float* bk       = (const float*)d_in[7];
    const float* Wv       = (const float*)d_in[8];
    const float* bv       = (const float*)d_in[9];
    const float* Wo       = (const float*)d_in[10];
    const float* bo       = (const float*)d_in[11];
    const float* We       = (const float*)d_in[12];
    const float* be       = (const float*)d_in[13];
    const float* g_ln     = (const float*)d_in[14];
    const float* b_ln     = (const float*)d_in[15];

    const size_t MAT = (size_t)MROWS * DIM;    // 786432
    const size_t WSQ = (size_t)DIM * DIM;      // 589824

    float* ws = (float*)d_ws;
    float* FQ    = ws;                 // -> reused as Z after attention
    float* FK    = ws + MAT;           // -> reused as ATT_bf (u16) after attention
    float* FV    = ws + 2 * MAT;       // also aliases prep partials (dead before gemm<0>)
    u16*   Fb    = (u16*)(ws + 3 * MAT);
    u16*   Ob    = Fb + MAT;
    u16*   W3    = Ob + MAT;           // 3 x [768][768] bf16, staged reuse
    char*  tail  = (char*)(W3 + 3 * WSQ);
    int*   idxb  = (int*)tail;
    float* distb = (float*)(tail + MROWS * KNN * 4);
    float* wdk   = (float*)(tail + 2 * MROWS * KNN * 4);
    float* ck    = wdk + DIM;
    float* wdv   = ck + DIM;
    float* cv    = wdv + DIM;
    float* Z     = FQ;
    u16*   ATTb  = (u16*)FK;
    float* part  = FV;                 // 16*4*768 floats, used only pre-gemm

    prep_partial_k<<<dim3(3, 16), 256, 0, stream>>>(Wd, bd, Wk, Wv, part);
    prep_reduce_k<<<3, 256, 0, stream>>>(part, bk, bv, wdk, ck, wdv, cv);
    topk_k<<<MROWS, 256, 0, stream>>>(pts, idxb, distb);
    convF_k<<<(int)(MAT / 1024), 256, 0, stream>>>(features, Fb);
    // WqT, WkT, WvT -> W3
    convT_k<<<dim3(12, 12, 3), 256, 0, stream>>>(Wq, Wk, Wv, W3, W3 + WSQ, W3 + 2 * WSQ);
    // FQ = F@Wq + bq ; FK = F@Wk ; FV = F@Wv (bk/bv folded into ck/cv)
    gemm_mfma_k<0><<<dim3(12, 16, 3), 256, 0, stream>>>(
        Fb, nullptr, W3, W3 + WSQ, W3 + 2 * WSQ, bq, nullptr, nullptr, FQ, FK, FV, nullptr);
    // W3 slots now dead: WoT -> W3[0], WeT_top -> W3[1], WeT_bot -> W3[2]
    convT_k<<<dim3(12, 12, 3), 256, 0, stream>>>(Wo, We, We + WSQ, W3, W3 + WSQ, W3 + 2 * WSQ);
    attn_k<<<MROWS, 256, 0, stream>>>(FQ, FK, FV, idxb, distb, wdk, ck, wdv, cv, Ob);
    // ATTb = bf16(O @ Wo + bo)
    gemm_mfma_k<1><<<dim3(12, 16, 1), 256, 0, stream>>>(
        Ob, nullptr, W3, nullptr, nullptr, bo, nullptr, nullptr, nullptr, nullptr, nullptr, ATTb);
    // Z = F@We_top + ATT@We_bot + be
    gemm_mfma_k<2><<<dim3(12, 16, 1), 256, 0, stream>>>(
        Fb, ATTb, W3 + WSQ, W3 + 2 * WSQ, nullptr, be, nullptr, nullptr, Z, nullptr, nullptr, nullptr);
    ln_silu_k<<<MROWS, 256, 0, stream>>>(Z, g_ln, b_ln, (float*)d_out);
}

// Round 4
// 125.196 us; speedup vs baseline: 2.4145x; 1.1438x over previous
//
#include <hip/hip_runtime.h>
#include <math.h>

#define NPTS 512
#define DIM  768
#define KNN  64
#define NH   8
#define HDIM 96
#define MROWS 1024   // B*NP
#define MPAD  1088   // MROWS + 2 (Wd,bd rows) padded to 64
#define WSQ   ((size_t)DIM * DIM)

typedef unsigned short u16;
typedef __attribute__((ext_vector_type(8))) short short8;
typedef __attribute__((ext_vector_type(4))) float f32x4;

__device__ __forceinline__ unsigned f2bf(float f) {
    unsigned u = __float_as_uint(f);
    return (u + 0x7fffu + ((u >> 16) & 1u)) >> 16;   // round-to-nearest-even
}

union SMu {
    float T[64][65];                                          // convT tile
    struct { float P[NPTS * 3]; unsigned long long keys[NPTS]; } tk;  // topk
};

// ---------------------------------------------------------------------------
// Megakernel: all independent prep in one launch.
//  blocks [0,768)      : features fp32 -> bf16 (Fb rows 0..1023)
//  blocks [768,816)    : Fb rows 1024(Wd) 1025(bd) 1026..1087(zero)
//  blocks [816,1840)   : per-point top-64 neighbors (bitonic)
//  blocks [1840,2704)  : 6 weight transposes fp32[k][n] -> bf16 W3[m][n][k]
// ---------------------------------------------------------------------------
__global__ __launch_bounds__(256) void mega_prep_k(
    const float* __restrict__ features, const float* __restrict__ pts,
    const float* __restrict__ Wd, const float* __restrict__ bd,
    const float* __restrict__ Wq, const float* __restrict__ Wk, const float* __restrict__ Wv,
    const float* __restrict__ Wo, const float* __restrict__ We,
    u16* __restrict__ Fb, u16* __restrict__ W3,
    int* __restrict__ idxb, float* __restrict__ distb)
{
    __shared__ SMu sm;
    int bid = blockIdx.x, tid = threadIdx.x;

    if (bid < 768) {                       // ---- convF
        int i = (bid * 256 + tid) * 4;
        float4 v = *(const float4*)&features[i];
        uint2 o;
        o.x = f2bf(v.x) | (f2bf(v.y) << 16);
        o.y = f2bf(v.z) | (f2bf(v.w) << 16);
        *(uint2*)&Fb[i] = o;
        return;
    }
    if (bid < 816) {                       // ---- extra A rows
        int flat = (bid - 768) * 1024 + tid * 4;   // 0..49151 over 64x768
        int r = flat / DIM, c = flat - r * DIM;    // 4-elem group stays in-row
        uint2 o; o.x = 0u; o.y = 0u;
        if (r == 0) {
            float4 v = *(const float4*)&Wd[c];
            o.x = f2bf(v.x) | (f2bf(v.y) << 16);
            o.y = f2bf(v.z) | (f2bf(v.w) << 16);
        } else if (r == 1) {
            float4 v = *(const float4*)&bd[c];
            o.x = f2bf(v.x) | (f2bf(v.y) << 16);
            o.y = f2bf(v.z) | (f2bf(v.w) << 16);
        }
        *(uint2*)&Fb[(size_t)(MROWS + r) * DIM + c] = o;
        return;
    }
    if (bid < 1840) {                      // ---- topk
        int bn = bid - 816;
        int b  = bn >> 9;
        int n  = bn & (NPTS - 1);
        const float* pb = pts + (size_t)b * NPTS * 3;
        for (int i = tid; i < NPTS * 3; i += 256) sm.tk.P[i] = pb[i];
        __syncthreads();
        float xn = sm.tk.P[n * 3], yn = sm.tk.P[n * 3 + 1], zn = sm.tk.P[n * 3 + 2];
        float sqn = xn * xn + yn * yn + zn * zn;
        for (int m = tid; m < NPTS; m += 256) {
            float xm = sm.tk.P[m * 3], ym = sm.tk.P[m * 3 + 1], zm = sm.tk.P[m * 3 + 2];
            float sqm = xm * xm + ym * ym + zm * zm;
            float d2 = sqn + sqm - 2.0f * (xn * xm + yn * ym + zn * zm);
            float dist = sqrtf(fmaxf(d2, 0.0f));
            sm.tk.keys[m] = (((unsigned long long)__float_as_uint(dist)) << 32) | (unsigned)m;
        }
        __syncthreads();
        for (int k = 2; k <= NPTS; k <<= 1) {
            for (int j = k >> 1; j > 0; j >>= 1) {
                for (int i = tid; i < NPTS; i += 256) {
                    int ixj = i ^ j;
                    if (ixj > i) {
                        bool asc = ((i & k) == 0);
                        unsigned long long a = sm.tk.keys[i], bb = sm.tk.keys[ixj];
                        if ((a > bb) == asc) { sm.tk.keys[i] = bb; sm.tk.keys[ixj] = a; }
                    }
                }
                __syncthreads();
            }
        }
        if (tid < KNN) {
            unsigned long long kk = sm.tk.keys[tid];
            idxb[(size_t)bn * KNN + tid]  = (int)(kk & 0xffffffffu);
            distb[(size_t)bn * KNN + tid] = __uint_as_float((unsigned)(kk >> 32));
        }
        return;
    }
    // ---- convT: 6 matrices x 144 (12x12) tile-blocks
    {
        int t = bid - 1840;
        int m = t / 144, r2 = t % 144;
        int by = r2 / 12, bx = r2 % 12;
        const float* S = (m == 0) ? Wq : (m == 1) ? Wk : (m == 2) ? Wv
                       : (m == 3) ? Wo : (m == 4) ? We : (We + WSQ);
        u16* D = W3 + (size_t)m * WSQ;
        int r0 = by * 64, c0 = bx * 64;
#pragma unroll
        for (int i = 0; i < 16; ++i) {
            int lin = tid + i * 256;
            int r = lin >> 6, c = lin & 63;
            sm.T[r][c] = S[(size_t)(r0 + r) * DIM + c0 + c];
        }
        __syncthreads();
#pragma unroll
        for (int i = 0; i < 16; ++i) {
            int lin = tid + i * 256;
            int c = lin >> 6, r = lin & 63;
            D[(size_t)(c0 + c) * DIM + r0 + r] = (u16)f2bf(sm.T[r][c]);
        }
    }
}

// ---------------------------------------------------------------------------
// bf16 MFMA GEMM, 64x64 tile, 4 waves (32x32 each, 2x2 frags), BK=64.
// B pre-transposed BT[n][k]. Grid y covers M/64 row tiles (M=1088 or 1024).
// MODE 0: z in {0,1,2}: C{0,1,2} = A0 @ BT{0,1,2} (+bias{z}), fp32 out
// MODE 1: Cb = bf16(A0 @ BT0 + bias0)
// MODE 2: C0 = A0 @ BT0 + A1 @ BT1 + bias0, fp32 out
// ---------------------------------------------------------------------------
template<int MODE>
__global__ __launch_bounds__(256) void gemm_mfma_k(
    const u16* __restrict__ A0, const u16* __restrict__ A1,
    const u16* __restrict__ B0, const u16* __restrict__ B1, const u16* __restrict__ B2,
    const float* __restrict__ bias0, const float* __restrict__ bias1, const float* __restrict__ bias2,
    float* __restrict__ C0, float* __restrict__ C1, float* __restrict__ C2,
    u16* __restrict__ Cb)
{
    const u16*   BT   = B0;
    const float* bias = bias0;
    float*       Cf   = C0;
    if (MODE == 0) {
        if (blockIdx.z == 1)      { BT = B1; bias = bias1; Cf = C1; }
        else if (blockIdx.z == 2) { BT = B2; bias = bias2; Cf = C2; }
    }

    __shared__ short As[64][72];   // 72-short stride: 16B-aligned, ~2-way banks
    __shared__ short Bs[64][72];

    int tid  = threadIdx.x;
    int wave = tid >> 6, lane = tid & 63;
    int wr = (wave >> 1) * 32, wc = (wave & 1) * 32;
    int l15 = lane & 15, kg = lane >> 4;
    int brow = blockIdx.y * 64, bcol = blockIdx.x * 64;

    f32x4 acc[2][2] = {};

    int srow = tid >> 3;            // 0..31
    int scol = (tid & 7) * 8;       // 0,8,..,56

    const int npair = (MODE == 2) ? 2 : 1;
    for (int p = 0; p < npair; ++p) {
        const u16* Ap = (MODE == 2 && p == 1) ? A1 : A0;
        const u16* Bp = (MODE == 2 && p == 1) ? B1 : BT;
        for (int k0 = 0; k0 < DIM; k0 += 64) {
#pragma unroll
            for (int s = 0; s < 2; ++s) {
                int r = srow + s * 32;
                *(short8*)&As[r][scol] = *(const short8*)&Ap[(size_t)(brow + r) * DIM + k0 + scol];
                *(short8*)&Bs[r][scol] = *(const short8*)&Bp[(size_t)(bcol + r) * DIM + k0 + scol];
            }
            __syncthreads();
#pragma unroll
            for (int kk = 0; kk < 2; ++kk) {
                short8 a0 = *(const short8*)&As[wr + l15][kk * 32 + kg * 8];
                short8 a1 = *(const short8*)&As[wr + 16 + l15][kk * 32 + kg * 8];
                short8 b0 = *(const short8*)&Bs[wc + l15][kk * 32 + kg * 8];
                short8 b1 = *(const short8*)&Bs[wc + 16 + l15][kk * 32 + kg * 8];
                acc[0][0] = __builtin_amdgcn_mfma_f32_16x16x32_bf16(a0, b0, acc[0][0], 0, 0, 0);
                acc[0][1] = __builtin_amdgcn_mfma_f32_16x16x32_bf16(a0, b1, acc[0][1], 0, 0, 0);
                acc[1][0] = __builtin_amdgcn_mfma_f32_16x16x32_bf16(a1, b0, acc[1][0], 0, 0, 0);
                acc[1][1] = __builtin_amdgcn_mfma_f32_16x16x32_bf16(a1, b1, acc[1][1], 0, 0, 0);
            }
            __syncthreads();
        }
    }

    // epilogue: D layout col = lane&15, row = (lane>>4)*4 + j   [m89/m91 verified]
#pragma unroll
    for (int m = 0; m < 2; ++m) {
#pragma unroll
        for (int n = 0; n < 2; ++n) {
            int col = bcol + wc + n * 16 + l15;
            float bv = bias ? bias[col] : 0.f;
#pragma unroll
            for (int j = 0; j < 4; ++j) {
                int row = brow + wr + m * 16 + kg * 4 + j;
                float v = acc[m][n][j] + bv;
                if (MODE == 1) Cb[(size_t)row * DIM + col] = (u16)f2bf(v);
                else           Cf[(size_t)row * DIM + col] = v;
            }
        }
    }
}

// ---------------------------------------------------------------------------
// Fused neighbor attention (fp32 math, bf16 output).
// wdk/ck/wdv/cv live in FK/FV rows 1024/1025 (computed by the QKV GEMM from
// the embedded Wd/bd rows); bk/bv added on the fly.
//   score_j = (q . FK[idx_j] + dist_j*(q.wdk) + (q.ck)) / sqrt(96)
//   o = sum_j attn_j*FV[idx_j] + (sum_j attn_j*dist_j)*wdv + cv
// ---------------------------------------------------------------------------
__global__ __launch_bounds__(256) void attn_k(
    const float* __restrict__ FQ, const float* __restrict__ FK, const float* __restrict__ FV,
    const int* __restrict__ idxb, const float* __restrict__ distb,
    const float* __restrict__ bk, const float* __restrict__ bv,
    u16* __restrict__ O)
{
    int bn = blockIdx.x;
    int b  = bn >> 9;
    int tid = threadIdx.x;
    int h = tid >> 5;
    int lane32 = tid & 31;

    const float* wdk = FK + (size_t)MROWS * DIM;
    const float* ckr = FK + (size_t)(MROWS + 1) * DIM;
    const float* wdv = FV + (size_t)MROWS * DIM;
    const float* cvr = FV + (size_t)(MROWS + 1) * DIM;

    __shared__ int   s_idx[KNN];
    __shared__ float s_dist[KNN];
    __shared__ float s_sc[NH][KNN];
    __shared__ float s_att[NH][KNN];
    __shared__ float s_qh[NH][2];
    __shared__ float s_sd[NH];

    if (tid < KNN) {
        s_idx[tid]  = idxb[(size_t)bn * KNN + tid];
        s_dist[tid] = distb[(size_t)bn * KNN + tid];
    }

    int e0 = tid * 3;
    const float* qrow = FQ + (size_t)bn * DIM;
    float q0 = qrow[e0], q1 = qrow[e0 + 1], q2 = qrow[e0 + 2];

    float pw = q0 * wdk[e0] + q1 * wdk[e0 + 1] + q2 * wdk[e0 + 2];
    float pc = q0 * (ckr[e0] + bk[e0]) + q1 * (ckr[e0 + 1] + bk[e0 + 1])
             + q2 * (ckr[e0 + 2] + bk[e0 + 2]);
#pragma unroll
    for (int off = 16; off; off >>= 1) {
        pw += __shfl_xor(pw, off);
        pc += __shfl_xor(pc, off);
    }
    if (lane32 == 0) { s_qh[h][0] = pw; s_qh[h][1] = pc; }
    __syncthreads();

    float qwdk = s_qh[h][0], qck = s_qh[h][1];
    const float invs = 0.10206207261596575f;  // 1/sqrt(96)
    int base = b * NPTS;

    for (int j = 0; j < KNN; ++j) {
        const float* kr = FK + (size_t)(base + s_idx[j]) * DIM;
        float p = q0 * kr[e0] + q1 * kr[e0 + 1] + q2 * kr[e0 + 2];
#pragma unroll
        for (int off = 16; off; off >>= 1) p += __shfl_xor(p, off);
        if (lane32 == 0) s_sc[h][j] = (p + s_dist[j] * qwdk + qck) * invs;
    }
    __syncthreads();

    float s0 = s_sc[h][lane32], s1 = s_sc[h][lane32 + 32];
    float mx = fmaxf(s0, s1);
#pragma unroll
    for (int off = 16; off; off >>= 1) mx = fmaxf(mx, __shfl_xor(mx, off));
    float ev0 = __expf(s0 - mx), ev1 = __expf(s1 - mx);
    float sum = ev0 + ev1;
#pragma unroll
    for (int off = 16; off; off >>= 1) sum += __shfl_xor(sum, off);
    float rs = 1.0f / sum;
    float a0 = ev0 * rs, a1 = ev1 * rs;
    s_att[h][lane32] = a0; s_att[h][lane32 + 32] = a1;
    float sd = a0 * s_dist[lane32] + a1 * s_dist[lane32 + 32];
#pragma unroll
    for (int off = 16; off; off >>= 1) sd += __shfl_xor(sd, off);
    if (lane32 == 0) s_sd[h] = sd;
    __syncthreads();

    float o0 = 0.f, o1 = 0.f, o2 = 0.f;
    for (int j = 0; j < KNN; ++j) {
        const float* vr = FV + (size_t)(base + s_idx[j]) * DIM;
        float a = s_att[h][j];
        o0 = fmaf(a, vr[e0], o0);
        o1 = fmaf(a, vr[e0 + 1], o1);
        o2 = fmaf(a, vr[e0 + 2], o2);
    }
    float sdh = s_sd[h];
    o0 += sdh * wdv[e0]     + (cvr[e0]     + bv[e0]);
    o1 += sdh * wdv[e0 + 1] + (cvr[e0 + 1] + bv[e0 + 1]);
    o2 += sdh * wdv[e0 + 2] + (cvr[e0 + 2] + bv[e0 + 2]);
    u16* orow = O + (size_t)bn * DIM;
    orow[e0]     = (u16)f2bf(o0);
    orow[e0 + 1] = (u16)f2bf(o1);
    orow[e0 + 2] = (u16)f2bf(o2);
}

// ---------------------------------------------------------------------------
// LayerNorm + SiLU per row of 768.
// ---------------------------------------------------------------------------
__global__ __launch_bounds__(256) void ln_silu_k(
    const float* __restrict__ Z, const float* __restrict__ g,
    const float* __restrict__ bta, float* __restrict__ out)
{
    int bn = blockIdx.x, tid = threadIdx.x;
    const float* z = Z + (size_t)bn * DIM;
    int e0 = tid * 3;
    float x0 = z[e0], x1 = z[e0 + 1], x2 = z[e0 + 2];
    float s = x0 + x1 + x2;
    float ss = x0 * x0 + x1 * x1 + x2 * x2;
    __shared__ float red[4][2];
#pragma unroll
    for (int off = 32; off; off >>= 1) {
        s  += __shfl_xor(s, off);
        ss += __shfl_xor(ss, off);
    }
    int w = tid >> 6;
    if ((tid & 63) == 0) { red[w][0] = s; red[w][1] = ss; }
    __syncthreads();
    s  = red[0][0] + red[1][0] + red[2][0] + red[3][0];
    ss = red[0][1] + red[1][1] + red[2][1] + red[3][1];
    float mean = s * (1.0f / DIM);
    float var  = ss * (1.0f / DIM) - mean * mean;
    float rstd = rsqrtf(var + 1e-5f);
    float* orow = out + (size_t)bn * DIM;
#pragma unroll
    for (int i = 0; i < 3; ++i) {
        int e = e0 + i;
        float x = (i == 0) ? x0 : (i == 1) ? x1 : x2;
        float y = (x - mean) * rstd * g[e] + bta[e];
        orow[e] = y / (1.0f + __expf(-y));
    }
}

// ---------------------------------------------------------------------------
extern "C" void kernel_launch(void* const* d_in, const int* in_sizes, int n_in,
                              void* d_out, int out_size, void* d_ws, size_t ws_size,
                              hipStream_t stream)
{
    const float* features = (const float*)d_in[0];
    const float* pts      = (const float*)d_in[1];
    const float* Wd       = (const float*)d_in[2];
    const float* bd       = (const float*)d_in[3];
    const float* Wq       = (const float*)d_in[4];
    const float* bq       = (const float*)d_in[5];
    const float* Wk       = (const float*)d_in[6];
    const float* bk       = (const float*)d_in[7];
    const float* Wv       = (const float*)d_in[8];
    const float* bv       = (const float*)d_in[9];
    const float* Wo       = (const float*)d_in[10];
    const float* bo       = (const float*)d_in[11];
    const float* We       = (const float*)d_in[12];
    const float* be       = (const float*)d_in[13];
    const float* g_ln     = (const float*)d_in[14];
    const float* b_ln     = (const float*)d_in[15];

    const size_t MAT  = (size_t)MROWS * DIM;   // 786432 (1024 rows)
    const size_t MATP = (size_t)MPAD  * DIM;   // 835584 (1088 rows)

    float* ws = (float*)d_ws;
    float* FQ   = ws;                  // [1088][768] f32; rows 0..1023 reused as Z
    float* FK   = ws + MATP;           // [1088][768] f32; low part reused as ATTb
    float* FV   = ws + 2 * MATP;       // [1088][768] f32
    u16*   Fb   = (u16*)(ws + 3 * MATP);   // [1088][768] bf16 (A matrix + Wd/bd rows)
    u16*   Ob   = Fb + MATP;           // [1024][768] bf16 (attention output)
    u16*   W3   = Ob + MATP;           // 6 x [768][768] bf16 transposed weights
    char*  tail = (char*)(W3 + 6 * WSQ);
    int*   idxb  = (int*)tail;
    float* distb = (float*)(tail + MAT / DIM * KNN * 4);  // MROWS*KNN ints then floats
    float* Z     = FQ;
    u16*   ATTb  = (u16*)FK;

    // 1) all independent prep in one launch
    mega_prep_k<<<2704, 256, 0, stream>>>(features, pts, Wd, bd, Wq, Wk, Wv, Wo, We,
                                          Fb, W3, idxb, distb);
    // 2) FQ = Fb@WqT + bq ; FK = Fb@WkT ; FV = Fb@WvT   (M=1088: rows 1024/1025
    //    of FK/FV are wdk/ck-bk and wdv/cv-bv from the embedded Wd/bd rows)
    gemm_mfma_k<0><<<dim3(12, MPAD / 64, 3), 256, 0, stream>>>(
        Fb, nullptr, W3, W3 + WSQ, W3 + 2 * WSQ, bq, nullptr, nullptr, FQ, FK, FV, nullptr);
    // 3) fused neighbor attention
    attn_k<<<MROWS, 256, 0, stream>>>(FQ, FK, FV, idxb, distb, bk, bv, Ob);
    // 4) ATTb = bf16(O @ Wo + bo)
    gemm_mfma_k<1><<<dim3(12, MROWS / 64, 1), 256, 0, stream>>>(
        Ob, nullptr, W3 + 3 * WSQ, nullptr, nullptr, bo, nullptr, nullptr,
        nullptr, nullptr, nullptr, ATTb);
    // 5) Z = F@We_top + ATT@We_bot + be
    gemm_mfma_k<2><<<dim3(12, MROWS / 64, 1), 256, 0, stream>>>(
        Fb, ATTb, W3 + 4 * WSQ, W3 + 5 * WSQ, nullptr, be, nullptr, nullptr,
        Z, nullptr, nullptr, nullptr);
    // 6) LayerNorm + SiLU
    ln_silu_k<<<MROWS, 256, 0, stream>>>(Z, g_ln, b_ln, (float*)d_out);
}

// Round 5
// 119.655 us; speedup vs baseline: 2.5263x; 1.0463x over previous
//
#include <hip/hip_runtime.h>
#include <math.h>

#define NPTS 512
#define DIM  768
#define KNN  64
#define NH   8
#define HDIM 96
#define MROWS 1024   // B*NP
#define MPAD  1088   // MROWS + 2 (Wd,bd rows) padded to 64
#define WOROWS 832   // 768 Wo rows + 1 bo row, padded to 64
#define WSQ   ((size_t)DIM * DIM)

typedef unsigned short u16;
typedef __attribute__((ext_vector_type(8))) short short8;
typedef __attribute__((ext_vector_type(4))) float f32x4;

__device__ __forceinline__ unsigned f2bf(float f) {
    unsigned u = __float_as_uint(f);
    return (u + 0x7fffu + ((u >> 16) & 1u)) >> 16;   // round-to-nearest-even
}
__device__ __forceinline__ float bf2f(u16 v) {
    return __uint_as_float(((unsigned)v) << 16);
}

union SMu {
    float T[64][65];                                          // convT tile
    struct { float P[NPTS * 3]; unsigned long long keys[NPTS]; } tk;  // topk
};

// ---------------------------------------------------------------------------
// Megakernel: all independent prep in one launch.
//  [0,768)     : features fp32 -> bf16 (Fb rows 0..1023)
//  [768,816)   : Fb rows 1024(Wd) 1025(bd) 1026..1087(zero)
//  [816,1440)  : Wob = bf16([Wo; bo; 0...])  (832x768, straight convert)
//  [1440,2464) : per-point top-64 neighbors (bitonic)
//  [2464,3184) : 5 transposes fp32[k][n] -> bf16 [n][k]: Wq,Wk,Wv,WeTop,WeBot
// ---------------------------------------------------------------------------
__global__ __launch_bounds__(256) void mega_prep_k(
    const float* __restrict__ features, const float* __restrict__ pts,
    const float* __restrict__ Wd, const float* __restrict__ bd,
    const float* __restrict__ Wq, const float* __restrict__ Wk, const float* __restrict__ Wv,
    const float* __restrict__ Wo, const float* __restrict__ bo, const float* __restrict__ We,
    u16* __restrict__ Fb, u16* __restrict__ Wob, u16* __restrict__ W3,
    int* __restrict__ idxb, float* __restrict__ distb)
{
    __shared__ SMu sm;
    int bid = blockIdx.x, tid = threadIdx.x;

    if (bid < 768) {                       // ---- convF
        int i = (bid * 256 + tid) * 4;
        float4 v = *(const float4*)&features[i];
        uint2 o;
        o.x = f2bf(v.x) | (f2bf(v.y) << 16);
        o.y = f2bf(v.z) | (f2bf(v.w) << 16);
        *(uint2*)&Fb[i] = o;
        return;
    }
    if (bid < 816) {                       // ---- extra A rows
        int flat = (bid - 768) * 1024 + tid * 4;   // 64x768 region
        int r = flat / DIM, c = flat - r * DIM;
        uint2 o; o.x = 0u; o.y = 0u;
        if (r == 0) {
            float4 v = *(const float4*)&Wd[c];
            o.x = f2bf(v.x) | (f2bf(v.y) << 16);
            o.y = f2bf(v.z) | (f2bf(v.w) << 16);
        } else if (r == 1) {
            float4 v = *(const float4*)&bd[c];
            o.x = f2bf(v.x) | (f2bf(v.y) << 16);
            o.y = f2bf(v.z) | (f2bf(v.w) << 16);
        }
        *(uint2*)&Fb[(size_t)(MROWS + r) * DIM + c] = o;
        return;
    }
    if (bid < 1440) {                      // ---- Wob = [Wo; bo; zeros]
        int flat = (bid - 816) * 1024 + tid * 4;   // 832x768 region
        int r = flat / DIM, c = flat - r * DIM;
        uint2 o; o.x = 0u; o.y = 0u;
        if (r < DIM) {
            float4 v = *(const float4*)&Wo[(size_t)r * DIM + c];
            o.x = f2bf(v.x) | (f2bf(v.y) << 16);
            o.y = f2bf(v.z) | (f2bf(v.w) << 16);
        } else if (r == DIM) {
            float4 v = *(const float4*)&bo[c];
            o.x = f2bf(v.x) | (f2bf(v.y) << 16);
            o.y = f2bf(v.z) | (f2bf(v.w) << 16);
        }
        *(uint2*)&Wob[(size_t)r * DIM + c] = o;
        return;
    }
    if (bid < 2464) {                      // ---- topk
        int bn = bid - 1440;
        int b  = bn >> 9;
        int n  = bn & (NPTS - 1);
        const float* pb = pts + (size_t)b * NPTS * 3;
        for (int i = tid; i < NPTS * 3; i += 256) sm.tk.P[i] = pb[i];
        __syncthreads();
        float xn = sm.tk.P[n * 3], yn = sm.tk.P[n * 3 + 1], zn = sm.tk.P[n * 3 + 2];
        float sqn = xn * xn + yn * yn + zn * zn;
        for (int m = tid; m < NPTS; m += 256) {
            float xm = sm.tk.P[m * 3], ym = sm.tk.P[m * 3 + 1], zm = sm.tk.P[m * 3 + 2];
            float sqm = xm * xm + ym * ym + zm * zm;
            float d2 = sqn + sqm - 2.0f * (xn * xm + yn * ym + zn * zm);
            float dist = sqrtf(fmaxf(d2, 0.0f));
            sm.tk.keys[m] = (((unsigned long long)__float_as_uint(dist)) << 32) | (unsigned)m;
        }
        __syncthreads();
        for (int k = 2; k <= NPTS; k <<= 1) {
            for (int j = k >> 1; j > 0; j >>= 1) {
                for (int i = tid; i < NPTS; i += 256) {
                    int ixj = i ^ j;
                    if (ixj > i) {
                        bool asc = ((i & k) == 0);
                        unsigned long long a = sm.tk.keys[i], bb = sm.tk.keys[ixj];
                        if ((a > bb) == asc) { sm.tk.keys[i] = bb; sm.tk.keys[ixj] = a; }
                    }
                }
                __syncthreads();
            }
        }
        if (tid < KNN) {
            unsigned long long kk = sm.tk.keys[tid];
            idxb[(size_t)bn * KNN + tid]  = (int)(kk & 0xffffffffu);
            distb[(size_t)bn * KNN + tid] = __uint_as_float((unsigned)(kk >> 32));
        }
        return;
    }
    // ---- convT: 5 matrices x 144 (12x12) tile-blocks
    {
        int t = bid - 2464;
        int m = t / 144, r2 = t % 144;
        int by = r2 / 12, bx = r2 % 12;
        const float* S = (m == 0) ? Wq : (m == 1) ? Wk : (m == 2) ? Wv
                       : (m == 3) ? We : (We + WSQ);
        u16* D = W3 + (size_t)m * WSQ;
        int r0 = by * 64, c0 = bx * 64;
#pragma unroll
        for (int i = 0; i < 16; ++i) {
            int lin = tid + i * 256;
            int r = lin >> 6, c = lin & 63;
            sm.T[r][c] = S[(size_t)(r0 + r) * DIM + c0 + c];
        }
        __syncthreads();
#pragma unroll
        for (int i = 0; i < 16; ++i) {
            int lin = tid + i * 256;
            int c = lin >> 6, r = lin & 63;
            D[(size_t)(c0 + c) * DIM + r0 + r] = (u16)f2bf(sm.T[r][c]);
        }
    }
}

// ---------------------------------------------------------------------------
// QKV + Weff GEMM, one launch, z in {0,1,2,3}:
//  z0: FQ  = Fb @ WqT + bq        (fp32, 1024 rows)
//  z1: FKb = bf16(Fb @ WkT)       (1088 rows; rows 1024/1025 = wdk/ck)
//  z2: FVb = bf16(Fb @ WvT)       (1088 rows; rows 1024/1025 = wdv/cv)
//  z3: Weff = [Wo;bo] @ WeBotT -> WeffT bf16 transposed (rows<768),
//      c_e[col] = bo @ WeBot (row 768, fp32)
// 64x64 tile, 4 waves (32x32 each, 2x2 frags), BK=64.
// ---------------------------------------------------------------------------
__global__ __launch_bounds__(256) void gemm_qkvw_k(
    const u16* __restrict__ Fb, const u16* __restrict__ Wob, const u16* __restrict__ W3,
    const float* __restrict__ bq,
    float* __restrict__ FQ, u16* __restrict__ FKb, u16* __restrict__ FVb,
    u16* __restrict__ WeffT, float* __restrict__ c_e)
{
    int z = blockIdx.z;
    if (z == 0 && blockIdx.y >= 16) return;
    if (z == 3 && blockIdx.y >= 13) return;
    const u16* A  = (z == 3) ? Wob : Fb;
    const u16* BT = W3 + (size_t)((z == 3) ? 4 : z) * WSQ;

    __shared__ short As[64][72];
    __shared__ short Bs[64][72];

    int tid  = threadIdx.x;
    int wave = tid >> 6, lane = tid & 63;
    int wr = (wave >> 1) * 32, wc = (wave & 1) * 32;
    int l15 = lane & 15, kg = lane >> 4;
    int brow = blockIdx.y * 64, bcol = blockIdx.x * 64;

    f32x4 acc[2][2] = {};

    int srow = tid >> 3;            // 0..31
    int scol = (tid & 7) * 8;       // 0,8,..,56

    for (int k0 = 0; k0 < DIM; k0 += 64) {
#pragma unroll
        for (int s = 0; s < 2; ++s) {
            int r = srow + s * 32;
            *(short8*)&As[r][scol] = *(const short8*)&A[(size_t)(brow + r) * DIM + k0 + scol];
            *(short8*)&Bs[r][scol] = *(const short8*)&BT[(size_t)(bcol + r) * DIM + k0 + scol];
        }
        __syncthreads();
#pragma unroll
        for (int kk = 0; kk < 2; ++kk) {
            short8 a0 = *(const short8*)&As[wr + l15][kk * 32 + kg * 8];
            short8 a1 = *(const short8*)&As[wr + 16 + l15][kk * 32 + kg * 8];
            short8 b0 = *(const short8*)&Bs[wc + l15][kk * 32 + kg * 8];
            short8 b1 = *(const short8*)&Bs[wc + 16 + l15][kk * 32 + kg * 8];
            acc[0][0] = __builtin_amdgcn_mfma_f32_16x16x32_bf16(a0, b0, acc[0][0], 0, 0, 0);
            acc[0][1] = __builtin_amdgcn_mfma_f32_16x16x32_bf16(a0, b1, acc[0][1], 0, 0, 0);
            acc[1][0] = __builtin_amdgcn_mfma_f32_16x16x32_bf16(a1, b0, acc[1][0], 0, 0, 0);
            acc[1][1] = __builtin_amdgcn_mfma_f32_16x16x32_bf16(a1, b1, acc[1][1], 0, 0, 0);
        }
        __syncthreads();
    }

    // D layout: col = lane&15, row = (lane>>4)*4 + j
#pragma unroll
    for (int m = 0; m < 2; ++m) {
#pragma unroll
        for (int n = 0; n < 2; ++n) {
            int col  = bcol + wc + n * 16 + l15;
            int row0 = brow + wr + m * 16 + kg * 4;
            if (z == 0) {
                float bv = bq[col];
#pragma unroll
                for (int j = 0; j < 4; ++j)
                    FQ[(size_t)(row0 + j) * DIM + col] = acc[m][n][j] + bv;
            } else if (z == 1) {
#pragma unroll
                for (int j = 0; j < 4; ++j)
                    FKb[(size_t)(row0 + j) * DIM + col] = (u16)f2bf(acc[m][n][j]);
            } else if (z == 2) {
#pragma unroll
                for (int j = 0; j < 4; ++j)
                    FVb[(size_t)(row0 + j) * DIM + col] = (u16)f2bf(acc[m][n][j]);
            } else {
                if (row0 + 3 < DIM) {
                    unsigned long long pk =
                          (unsigned long long)f2bf(acc[m][n][0])
                        | ((unsigned long long)f2bf(acc[m][n][1]) << 16)
                        | ((unsigned long long)f2bf(acc[m][n][2]) << 32)
                        | ((unsigned long long)f2bf(acc[m][n][3]) << 48);
                    *(unsigned long long*)&WeffT[(size_t)col * DIM + row0] = pk;
                } else {
#pragma unroll
                    for (int j = 0; j < 4; ++j) {
                        int row = row0 + j;
                        if (row < DIM)       WeffT[(size_t)col * DIM + row] = (u16)f2bf(acc[m][n][j]);
                        else if (row == DIM) c_e[col] = acc[m][n][j];
                    }
                }
            }
        }
    }
}

// ---------------------------------------------------------------------------
// Final GEMM: Z = Fb @ WeTopT + Ob @ WeffT + (c_e + be)   (fp32 out)
// ---------------------------------------------------------------------------
__global__ __launch_bounds__(256) void gemm_final_k(
    const u16* __restrict__ Fb, const u16* __restrict__ Ob,
    const u16* __restrict__ WeTopT, const u16* __restrict__ WeffT,
    const float* __restrict__ c_e, const float* __restrict__ be,
    float* __restrict__ Z)
{
    __shared__ short As[64][72];
    __shared__ short Bs[64][72];

    int tid  = threadIdx.x;
    int wave = tid >> 6, lane = tid & 63;
    int wr = (wave >> 1) * 32, wc = (wave & 1) * 32;
    int l15 = lane & 15, kg = lane >> 4;
    int brow = blockIdx.y * 64, bcol = blockIdx.x * 64;

    f32x4 acc[2][2] = {};

    int srow = tid >> 3;
    int scol = (tid & 7) * 8;

#pragma unroll
    for (int p = 0; p < 2; ++p) {
        const u16* Ap = p ? Ob : Fb;
        const u16* Bp = p ? WeffT : WeTopT;
        for (int k0 = 0; k0 < DIM; k0 += 64) {
#pragma unroll
            for (int s = 0; s < 2; ++s) {
                int r = srow + s * 32;
                *(short8*)&As[r][scol] = *(const short8*)&Ap[(size_t)(brow + r) * DIM + k0 + scol];
                *(short8*)&Bs[r][scol] = *(const short8*)&Bp[(size_t)(bcol + r) * DIM + k0 + scol];
            }
            __syncthreads();
#pragma unroll
            for (int kk = 0; kk < 2; ++kk) {
                short8 a0 = *(const short8*)&As[wr + l15][kk * 32 + kg * 8];
                short8 a1 = *(const short8*)&As[wr + 16 + l15][kk * 32 + kg * 8];
                short8 b0 = *(const short8*)&Bs[wc + l15][kk * 32 + kg * 8];
                short8 b1 = *(const short8*)&Bs[wc + 16 + l15][kk * 32 + kg * 8];
                acc[0][0] = __builtin_amdgcn_mfma_f32_16x16x32_bf16(a0, b0, acc[0][0], 0, 0, 0);
                acc[0][1] = __builtin_amdgcn_mfma_f32_16x16x32_bf16(a0, b1, acc[0][1], 0, 0, 0);
                acc[1][0] = __builtin_amdgcn_mfma_f32_16x16x32_bf16(a1, b0, acc[1][0], 0, 0, 0);
                acc[1][1] = __builtin_amdgcn_mfma_f32_16x16x32_bf16(a1, b1, acc[1][1], 0, 0, 0);
            }
            __syncthreads();
        }
    }

#pragma unroll
    for (int m = 0; m < 2; ++m) {
#pragma unroll
        for (int n = 0; n < 2; ++n) {
            int col = bcol + wc + n * 16 + l15;
            float bv = c_e[col] + be[col];
#pragma unroll
            for (int j = 0; j < 4; ++j) {
                int row = brow + wr + m * 16 + kg * 4 + j;
                Z[(size_t)row * DIM + col] = acc[m][n][j] + bv;
            }
        }
    }
}

// ---------------------------------------------------------------------------
// Fused neighbor attention (fp32 math, bf16 K/V inputs, bf16 output).
// wdk/ck/wdv/cv live in FKb/FVb rows 1024/1025; bk/bv added on the fly.
// ---------------------------------------------------------------------------
__global__ __launch_bounds__(256) void attn_k(
    const float* __restrict__ FQ, const u16* __restrict__ FKb, const u16* __restrict__ FVb,
    const int* __restrict__ idxb, const float* __restrict__ distb,
    const float* __restrict__ bk, const float* __restrict__ bv,
    u16* __restrict__ O)
{
    int bn = blockIdx.x;
    int b  = bn >> 9;
    int tid = threadIdx.x;
    int h = tid >> 5;
    int lane32 = tid & 31;

    const u16* wdk = FKb + (size_t)MROWS * DIM;
    const u16* ckr = FKb + (size_t)(MROWS + 1) * DIM;
    const u16* wdv = FVb + (size_t)MROWS * DIM;
    const u16* cvr = FVb + (size_t)(MROWS + 1) * DIM;

    __shared__ int   s_idx[KNN];
    __shared__ float s_dist[KNN];
    __shared__ float s_sc[NH][KNN];
    __shared__ float s_att[NH][KNN];
    __shared__ float s_qh[NH][2];
    __shared__ float s_sd[NH];

    if (tid < KNN) {
        s_idx[tid]  = idxb[(size_t)bn * KNN + tid];
        s_dist[tid] = distb[(size_t)bn * KNN + tid];
    }

    int e0 = tid * 3;
    const float* qrow = FQ + (size_t)bn * DIM;
    float q0 = qrow[e0], q1 = qrow[e0 + 1], q2 = qrow[e0 + 2];

    float pw = q0 * bf2f(wdk[e0]) + q1 * bf2f(wdk[e0 + 1]) + q2 * bf2f(wdk[e0 + 2]);
    float pc = q0 * (bf2f(ckr[e0]) + bk[e0]) + q1 * (bf2f(ckr[e0 + 1]) + bk[e0 + 1])
             + q2 * (bf2f(ckr[e0 + 2]) + bk[e0 + 2]);
#pragma unroll
    for (int off = 16; off; off >>= 1) {
        pw += __shfl_xor(pw, off);
        pc += __shfl_xor(pc, off);
    }
    if (lane32 == 0) { s_qh[h][0] = pw; s_qh[h][1] = pc; }
    __syncthreads();

    float qwdk = s_qh[h][0], qck = s_qh[h][1];
    const float invs = 0.10206207261596575f;  // 1/sqrt(96)
    int base = b * NPTS;

    for (int j = 0; j < KNN; ++j) {
        const u16* kr = FKb + (size_t)(base + s_idx[j]) * DIM;
        float p = q0 * bf2f(kr[e0]) + q1 * bf2f(kr[e0 + 1]) + q2 * bf2f(kr[e0 + 2]);
#pragma unroll
        for (int off = 16; off; off >>= 1) p += __shfl_xor(p, off);
        if (lane32 == 0) s_sc[h][j] = (p + s_dist[j] * qwdk + qck) * invs;
    }
    __syncthreads();

    float s0 = s_sc[h][lane32], s1 = s_sc[h][lane32 + 32];
    float mx = fmaxf(s0, s1);
#pragma unroll
    for (int off = 16; off; off >>= 1) mx = fmaxf(mx, __shfl_xor(mx, off));
    float ev0 = __expf(s0 - mx), ev1 = __expf(s1 - mx);
    float sum = ev0 + ev1;
#pragma unroll
    for (int off = 16; off; off >>= 1) sum += __shfl_xor(sum, off);
    float rs = 1.0f / sum;
    float a0 = ev0 * rs, a1 = ev1 * rs;
    s_att[h][lane32] = a0; s_att[h][lane32 + 32] = a1;
    float sd = a0 * s_dist[lane32] + a1 * s_dist[lane32 + 32];
#pragma unroll
    for (int off = 16; off; off >>= 1) sd += __shfl_xor(sd, off);
    if (lane32 == 0) s_sd[h] = sd;
    __syncthreads();

    float o0 = 0.f, o1 = 0.f, o2 = 0.f;
    for (int j = 0; j < KNN; ++j) {
        const u16* vr = FVb + (size_t)(base + s_idx[j]) * DIM;
        float a = s_att[h][j];
        o0 = fmaf(a, bf2f(vr[e0]), o0);
        o1 = fmaf(a, bf2f(vr[e0 + 1]), o1);
        o2 = fmaf(a, bf2f(vr[e0 + 2]), o2);
    }
    float sdh = s_sd[h];
    o0 += sdh * bf2f(wdv[e0])     + (bf2f(cvr[e0])     + bv[e0]);
    o1 += sdh * bf2f(wdv[e0 + 1]) + (bf2f(cvr[e0 + 1]) + bv[e0 + 1]);
    o2 += sdh * bf2f(wdv[e0 + 2]) + (bf2f(cvr[e0 + 2]) + bv[e0 + 2]);
    u16* orow = O + (size_t)bn * DIM;
    orow[e0]     = (u16)f2bf(o0);
    orow[e0 + 1] = (u16)f2bf(o1);
    orow[e0 + 2] = (u16)f2bf(o2);
}

// ---------------------------------------------------------------------------
// LayerNorm + SiLU per row of 768.
// ---------------------------------------------------------------------------
__global__ __launch_bounds__(256) void ln_silu_k(
    const float* __restrict__ Z, const float* __restrict__ g,
    const float* __restrict__ bta, float* __restrict__ out)
{
    int bn = blockIdx.x, tid = threadIdx.x;
    const float* z = Z + (size_t)bn * DIM;
    int e0 = tid * 3;
    float x0 = z[e0], x1 = z[e0 + 1], x2 = z[e0 + 2];
    float s = x0 + x1 + x2;
    float ss = x0 * x0 + x1 * x1 + x2 * x2;
    __shared__ float red[4][2];
#pragma unroll
    for (int off = 32; off; off >>= 1) {
        s  += __shfl_xor(s, off);
        ss += __shfl_xor(ss, off);
    }
    int w = tid >> 6;
    if ((tid & 63) == 0) { red[w][0] = s; red[w][1] = ss; }
    __syncthreads();
    s  = red[0][0] + red[1][0] + red[2][0] + red[3][0];
    ss = red[0][1] + red[1][1] + red[2][1] + red[3][1];
    float mean = s * (1.0f / DIM);
    float var  = ss * (1.0f / DIM) - mean * mean;
    float rstd = rsqrtf(var + 1e-5f);
    float* orow = out + (size_t)bn * DIM;
#pragma unroll
    for (int i = 0; i < 3; ++i) {
        int e = e0 + i;
        float x = (i == 0) ? x0 : (i == 1) ? x1 : x2;
        float y = (x - mean) * rstd * g[e] + bta[e];
        orow[e] = y / (1.0f + __expf(-y));
    }
}

// ---------------------------------------------------------------------------
extern "C" void kernel_launch(void* const* d_in, const int* in_sizes, int n_in,
                              void* d_out, int out_size, void* d_ws, size_t ws_size,
                              hipStream_t stream)
{
    const float* features = (const float*)d_in[0];
    const float* pts      = (const float*)d_in[1];
    const float* Wd       = (const float*)d_in[2];
    const float* bd       = (const float*)d_in[3];
    const float* Wq       = (const float*)d_in[4];
    const float* bq       = (const float*)d_in[5];
    const float* Wk       = (const float*)d_in[6];
    const float* bk       = (const float*)d_in[7];
    const float* Wv       = (const float*)d_in[8];
    const float* bv       = (const float*)d_in[9];
    const float* Wo       = (const float*)d_in[10];
    const float* bo       = (const float*)d_in[11];
    const float* We       = (const float*)d_in[12];
    const float* be       = (const float*)d_in[13];
    const float* g_ln     = (const float*)d_in[14];
    const float* b_ln     = (const float*)d_in[15];

    const size_t MAT  = (size_t)MROWS * DIM;   // 786432
    const size_t MATP = (size_t)MPAD  * DIM;   // 835584

    float* ws = (float*)d_ws;
    float* FQ    = ws;                       // [1088][768] f32; rows 0..1023 reused as Z
    u16*   FKb   = (u16*)(ws + MATP);        // [1088][768] bf16 (rows 1024/1025 = wdk/ck)
    u16*   FVb   = FKb + MATP;               // [1088][768] bf16 (rows 1024/1025 = wdv/cv)
    u16*   Fb    = FVb + MATP;               // [1088][768] bf16 (features + Wd/bd rows)
    u16*   Ob    = Fb + MATP;                // [1024][768] bf16 (attention output)
    u16*   Wob   = Ob + MAT;                 // [832][768] bf16 ([Wo; bo; 0])
    u16*   W3    = Wob + (size_t)WOROWS * DIM;  // 5 x [768][768] bf16 transposed
    u16*   WeffT = W3 + 5 * WSQ;             // [768][768] bf16 (Wo@WeBot)^T
    float* c_e   = (float*)(WeffT + WSQ);    // [768] f32 (bo@WeBot)
    int*   idxb  = (int*)(c_e + DIM);
    float* distb = (float*)(idxb + (size_t)MROWS * KNN);
    float* Z     = FQ;

    // 1) all independent prep in one launch
    mega_prep_k<<<3184, 256, 0, stream>>>(features, pts, Wd, bd, Wq, Wk, Wv, Wo, bo, We,
                                          Fb, Wob, W3, idxb, distb);
    // 2) QKV projections + Weff precompute, one launch
    gemm_qkvw_k<<<dim3(12, 17, 4), 256, 0, stream>>>(
        Fb, Wob, W3, bq, FQ, FKb, FVb, WeffT, c_e);
    // 3) fused neighbor attention
    attn_k<<<MROWS, 256, 0, stream>>>(FQ, FKb, FVb, idxb, distb, bk, bv, Ob);
    // 4) Z = Fb@WeTopT + Ob@WeffT + (c_e + be)
    gemm_final_k<<<dim3(12, 16), 256, 0, stream>>>(
        Fb, Ob, W3 + 3 * WSQ, WeffT, c_e, be, Z);
    // 5) LayerNorm + SiLU
    ln_silu_k<<<MROWS, 256, 0, stream>>>(Z, g_ln, b_ln, (float*)d_out);
}

// Round 6
// 104.577 us; speedup vs baseline: 2.8905x; 1.1442x over previous
//
#include <hip/hip_runtime.h>
#include <math.h>

#define NPTS 512
#define DIM  768
#define KNN  64
#define NH   8
#define HDIM 96
#define MROWS 1024   // B*NP
#define MPAD  1088   // MROWS + 2 (Wd,bd rows) padded to 64
#define WOROWS 832   // 768 Wo rows + 1 bo row, padded to 64
#define WSQ   ((size_t)DIM * DIM)

typedef unsigned short u16;
typedef __attribute__((ext_vector_type(8))) short short8;
typedef __attribute__((ext_vector_type(4))) float f32x4;

__device__ __forceinline__ unsigned f2bf(float f) {
    unsigned u = __float_as_uint(f);
    return (u + 0x7fffu + ((u >> 16) & 1u)) >> 16;   // round-to-nearest-even
}
__device__ __forceinline__ float bf2f(u16 v) {
    return __uint_as_float(((unsigned)v) << 16);
}

union SMu {
    float T[64][65];                                          // convT tile
    struct { float P[NPTS * 3]; unsigned long long keys[NPTS]; } tk;  // topk
};

// ---------------------------------------------------------------------------
// Megakernel: all independent prep in one launch.
//  [0,768)     : features fp32 -> bf16 (Fb rows 0..1023)
//  [768,816)   : Fb rows 1024(Wd) 1025(bd) 1026..1087(zero)
//  [816,1440)  : Wob = bf16([Wo; bo; 0...])  (832x768, straight convert)
//  [1440,2464) : per-point top-64 neighbors (bitonic)
//  [2464,3184) : 5 transposes fp32[k][n] -> bf16 [n][k]: Wq,Wk,Wv,WeTop,WeBot
// ---------------------------------------------------------------------------
__global__ __launch_bounds__(256) void mega_prep_k(
    const float* __restrict__ features, const float* __restrict__ pts,
    const float* __restrict__ Wd, const float* __restrict__ bd,
    const float* __restrict__ Wq, const float* __restrict__ Wk, const float* __restrict__ Wv,
    const float* __restrict__ Wo, const float* __restrict__ bo, const float* __restrict__ We,
    u16* __restrict__ Fb, u16* __restrict__ Wob, u16* __restrict__ W3,
    int* __restrict__ idxb, float* __restrict__ distb)
{
    __shared__ SMu sm;
    int bid = blockIdx.x, tid = threadIdx.x;

    if (bid < 768) {                       // ---- convF
        int i = (bid * 256 + tid) * 4;
        float4 v = *(const float4*)&features[i];
        uint2 o;
        o.x = f2bf(v.x) | (f2bf(v.y) << 16);
        o.y = f2bf(v.z) | (f2bf(v.w) << 16);
        *(uint2*)&Fb[i] = o;
        return;
    }
    if (bid < 816) {                       // ---- extra A rows
        int flat = (bid - 768) * 1024 + tid * 4;   // 64x768 region
        int r = flat / DIM, c = flat - r * DIM;
        uint2 o; o.x = 0u; o.y = 0u;
        if (r == 0) {
            float4 v = *(const float4*)&Wd[c];
            o.x = f2bf(v.x) | (f2bf(v.y) << 16);
            o.y = f2bf(v.z) | (f2bf(v.w) << 16);
        } else if (r == 1) {
            float4 v = *(const float4*)&bd[c];
            o.x = f2bf(v.x) | (f2bf(v.y) << 16);
            o.y = f2bf(v.z) | (f2bf(v.w) << 16);
        }
        *(uint2*)&Fb[(size_t)(MROWS + r) * DIM + c] = o;
        return;
    }
    if (bid < 1440) {                      // ---- Wob = [Wo; bo; zeros]
        int flat = (bid - 816) * 1024 + tid * 4;   // 832x768 region
        int r = flat / DIM, c = flat - r * DIM;
        uint2 o; o.x = 0u; o.y = 0u;
        if (r < DIM) {
            float4 v = *(const float4*)&Wo[(size_t)r * DIM + c];
            o.x = f2bf(v.x) | (f2bf(v.y) << 16);
            o.y = f2bf(v.z) | (f2bf(v.w) << 16);
        } else if (r == DIM) {
            float4 v = *(const float4*)&bo[c];
            o.x = f2bf(v.x) | (f2bf(v.y) << 16);
            o.y = f2bf(v.z) | (f2bf(v.w) << 16);
        }
        *(uint2*)&Wob[(size_t)r * DIM + c] = o;
        return;
    }
    if (bid < 2464) {                      // ---- topk
        int bn = bid - 1440;
        int b  = bn >> 9;
        int n  = bn & (NPTS - 1);
        const float* pb = pts + (size_t)b * NPTS * 3;
        for (int i = tid; i < NPTS * 3; i += 256) sm.tk.P[i] = pb[i];
        __syncthreads();
        float xn = sm.tk.P[n * 3], yn = sm.tk.P[n * 3 + 1], zn = sm.tk.P[n * 3 + 2];
        float sqn = xn * xn + yn * yn + zn * zn;
        for (int m = tid; m < NPTS; m += 256) {
            float xm = sm.tk.P[m * 3], ym = sm.tk.P[m * 3 + 1], zm = sm.tk.P[m * 3 + 2];
            float sqm = xm * xm + ym * ym + zm * zm;
            float d2 = sqn + sqm - 2.0f * (xn * xm + yn * ym + zn * zm);
            float dist = sqrtf(fmaxf(d2, 0.0f));
            sm.tk.keys[m] = (((unsigned long long)__float_as_uint(dist)) << 32) | (unsigned)m;
        }
        __syncthreads();
        for (int k = 2; k <= NPTS; k <<= 1) {
            for (int j = k >> 1; j > 0; j >>= 1) {
                for (int i = tid; i < NPTS; i += 256) {
                    int ixj = i ^ j;
                    if (ixj > i) {
                        bool asc = ((i & k) == 0);
                        unsigned long long a = sm.tk.keys[i], bb = sm.tk.keys[ixj];
                        if ((a > bb) == asc) { sm.tk.keys[i] = bb; sm.tk.keys[ixj] = a; }
                    }
                }
                __syncthreads();
            }
        }
        if (tid < KNN) {
            unsigned long long kk = sm.tk.keys[tid];
            idxb[(size_t)bn * KNN + tid]  = (int)(kk & 0xffffffffu);
            distb[(size_t)bn * KNN + tid] = __uint_as_float((unsigned)(kk >> 32));
        }
        return;
    }
    // ---- convT: 5 matrices x 144 (12x12) tile-blocks
    {
        int t = bid - 2464;
        int m = t / 144, r2 = t % 144;
        int by = r2 / 12, bx = r2 % 12;
        const float* S = (m == 0) ? Wq : (m == 1) ? Wk : (m == 2) ? Wv
                       : (m == 3) ? We : (We + WSQ);
        u16* D = W3 + (size_t)m * WSQ;
        int r0 = by * 64, c0 = bx * 64;
#pragma unroll
        for (int i = 0; i < 16; ++i) {
            int lin = tid + i * 256;
            int r = lin >> 6, c = lin & 63;
            sm.T[r][c] = S[(size_t)(r0 + r) * DIM + c0 + c];
        }
        __syncthreads();
#pragma unroll
        for (int i = 0; i < 16; ++i) {
            int lin = tid + i * 256;
            int c = lin >> 6, r = lin & 63;
            D[(size_t)(c0 + c) * DIM + r0 + r] = (u16)f2bf(sm.T[r][c]);
        }
    }
}

// ---------------------------------------------------------------------------
// QKV + Weff GEMM, one launch, z in {0,1,2,3}:
//  z0: FQ  = Fb @ WqT + bq        (fp32, 1024 rows)
//  z1: FKb = bf16(Fb @ WkT)       (1088 rows; rows 1024/1025 = wdk/ck)
//  z2: FVb = bf16(Fb @ WvT)       (1088 rows; rows 1024/1025 = wdv/cv)
//  z3: Weff = [Wo;bo] @ WeBotT -> WeffT bf16 transposed (rows<768),
//      c_e[col] = bo @ WeBot (row 768, fp32)
// ---------------------------------------------------------------------------
__global__ __launch_bounds__(256) void gemm_qkvw_k(
    const u16* __restrict__ Fb, const u16* __restrict__ Wob, const u16* __restrict__ W3,
    const float* __restrict__ bq,
    float* __restrict__ FQ, u16* __restrict__ FKb, u16* __restrict__ FVb,
    u16* __restrict__ WeffT, float* __restrict__ c_e)
{
    int z = blockIdx.z;
    if (z == 0 && blockIdx.y >= 16) return;
    if (z == 3 && blockIdx.y >= 13) return;
    const u16* A  = (z == 3) ? Wob : Fb;
    const u16* BT = W3 + (size_t)((z == 3) ? 4 : z) * WSQ;

    __shared__ short As[64][72];
    __shared__ short Bs[64][72];

    int tid  = threadIdx.x;
    int wave = tid >> 6, lane = tid & 63;
    int wr = (wave >> 1) * 32, wc = (wave & 1) * 32;
    int l15 = lane & 15, kg = lane >> 4;
    int brow = blockIdx.y * 64, bcol = blockIdx.x * 64;

    f32x4 acc[2][2] = {};

    int srow = tid >> 3;            // 0..31
    int scol = (tid & 7) * 8;       // 0,8,..,56

    for (int k0 = 0; k0 < DIM; k0 += 64) {
#pragma unroll
        for (int s = 0; s < 2; ++s) {
            int r = srow + s * 32;
            *(short8*)&As[r][scol] = *(const short8*)&A[(size_t)(brow + r) * DIM + k0 + scol];
            *(short8*)&Bs[r][scol] = *(const short8*)&BT[(size_t)(bcol + r) * DIM + k0 + scol];
        }
        __syncthreads();
#pragma unroll
        for (int kk = 0; kk < 2; ++kk) {
            short8 a0 = *(const short8*)&As[wr + l15][kk * 32 + kg * 8];
            short8 a1 = *(const short8*)&As[wr + 16 + l15][kk * 32 + kg * 8];
            short8 b0 = *(const short8*)&Bs[wc + l15][kk * 32 + kg * 8];
            short8 b1 = *(const short8*)&Bs[wc + 16 + l15][kk * 32 + kg * 8];
            acc[0][0] = __builtin_amdgcn_mfma_f32_16x16x32_bf16(a0, b0, acc[0][0], 0, 0, 0);
            acc[0][1] = __builtin_amdgcn_mfma_f32_16x16x32_bf16(a0, b1, acc[0][1], 0, 0, 0);
            acc[1][0] = __builtin_amdgcn_mfma_f32_16x16x32_bf16(a1, b0, acc[1][0], 0, 0, 0);
            acc[1][1] = __builtin_amdgcn_mfma_f32_16x16x32_bf16(a1, b1, acc[1][1], 0, 0, 0);
        }
        __syncthreads();
    }

    // D layout: col = lane&15, row = (lane>>4)*4 + j
#pragma unroll
    for (int m = 0; m < 2; ++m) {
#pragma unroll
        for (int n = 0; n < 2; ++n) {
            int col  = bcol + wc + n * 16 + l15;
            int row0 = brow + wr + m * 16 + kg * 4;
            if (z == 0) {
                float bv = bq[col];
#pragma unroll
                for (int j = 0; j < 4; ++j)
                    FQ[(size_t)(row0 + j) * DIM + col] = acc[m][n][j] + bv;
            } else if (z == 1) {
#pragma unroll
                for (int j = 0; j < 4; ++j)
                    FKb[(size_t)(row0 + j) * DIM + col] = (u16)f2bf(acc[m][n][j]);
            } else if (z == 2) {
#pragma unroll
                for (int j = 0; j < 4; ++j)
                    FVb[(size_t)(row0 + j) * DIM + col] = (u16)f2bf(acc[m][n][j]);
            } else {
                if (row0 + 3 < DIM) {
                    unsigned long long pk =
                          (unsigned long long)f2bf(acc[m][n][0])
                        | ((unsigned long long)f2bf(acc[m][n][1]) << 16)
                        | ((unsigned long long)f2bf(acc[m][n][2]) << 32)
                        | ((unsigned long long)f2bf(acc[m][n][3]) << 48);
                    *(unsigned long long*)&WeffT[(size_t)col * DIM + row0] = pk;
                } else {
#pragma unroll
                    for (int j = 0; j < 4; ++j) {
                        int row = row0 + j;
                        if (row < DIM)       WeffT[(size_t)col * DIM + row] = (u16)f2bf(acc[m][n][j]);
                        else if (row == DIM) c_e[col] = acc[m][n][j];
                    }
                }
            }
        }
    }
}

// ---------------------------------------------------------------------------
// Final GEMM: Z = Fb @ WeTopT + Ob @ WeffT + (c_e + be)   (fp32 out)
// ---------------------------------------------------------------------------
__global__ __launch_bounds__(256) void gemm_final_k(
    const u16* __restrict__ Fb, const u16* __restrict__ Ob,
    const u16* __restrict__ WeTopT, const u16* __restrict__ WeffT,
    const float* __restrict__ c_e, const float* __restrict__ be,
    float* __restrict__ Z)
{
    __shared__ short As[64][72];
    __shared__ short Bs[64][72];

    int tid  = threadIdx.x;
    int wave = tid >> 6, lane = tid & 63;
    int wr = (wave >> 1) * 32, wc = (wave & 1) * 32;
    int l15 = lane & 15, kg = lane >> 4;
    int brow = blockIdx.y * 64, bcol = blockIdx.x * 64;

    f32x4 acc[2][2] = {};

    int srow = tid >> 3;
    int scol = (tid & 7) * 8;

#pragma unroll
    for (int p = 0; p < 2; ++p) {
        const u16* Ap = p ? Ob : Fb;
        const u16* Bp = p ? WeffT : WeTopT;
        for (int k0 = 0; k0 < DIM; k0 += 64) {
#pragma unroll
            for (int s = 0; s < 2; ++s) {
                int r = srow + s * 32;
                *(short8*)&As[r][scol] = *(const short8*)&Ap[(size_t)(brow + r) * DIM + k0 + scol];
                *(short8*)&Bs[r][scol] = *(const short8*)&Bp[(size_t)(bcol + r) * DIM + k0 + scol];
            }
            __syncthreads();
#pragma unroll
            for (int kk = 0; kk < 2; ++kk) {
                short8 a0 = *(const short8*)&As[wr + l15][kk * 32 + kg * 8];
                short8 a1 = *(const short8*)&As[wr + 16 + l15][kk * 32 + kg * 8];
                short8 b0 = *(const short8*)&Bs[wc + l15][kk * 32 + kg * 8];
                short8 b1 = *(const short8*)&Bs[wc + 16 + l15][kk * 32 + kg * 8];
                acc[0][0] = __builtin_amdgcn_mfma_f32_16x16x32_bf16(a0, b0, acc[0][0], 0, 0, 0);
                acc[0][1] = __builtin_amdgcn_mfma_f32_16x16x32_bf16(a0, b1, acc[0][1], 0, 0, 0);
                acc[1][0] = __builtin_amdgcn_mfma_f32_16x16x32_bf16(a1, b0, acc[1][0], 0, 0, 0);
                acc[1][1] = __builtin_amdgcn_mfma_f32_16x16x32_bf16(a1, b1, acc[1][1], 0, 0, 0);
            }
            __syncthreads();
        }
    }

#pragma unroll
    for (int m = 0; m < 2; ++m) {
#pragma unroll
        for (int n = 0; n < 2; ++n) {
            int col = bcol + wc + n * 16 + l15;
            float bv = c_e[col] + be[col];
#pragma unroll
            for (int j = 0; j < 4; ++j) {
                int row = brow + wr + m * 16 + kg * 4 + j;
                Z[(size_t)row * DIM + col] = acc[m][n][j] + bv;
            }
        }
    }
}

// ---------------------------------------------------------------------------
// Fused neighbor attention, shuffle-free score phase. 512 threads/block.
//  phase A: stage idx/dist + Q row (fp32) into LDS
//  phase B: per-head qwdk/qck (one wave per head, 64-lane reduce)
//  phase C: scores — thread (j=tid>>3, h=tid&7) computes full 96-dot alone
//  phase D: softmax — one wave per head, lane = neighbor
//  phase E: PV — threads 0..383 own element-pairs, u32 bf16x2 loads
// ---------------------------------------------------------------------------
__global__ __launch_bounds__(512) void attn_k(
    const float* __restrict__ FQ, const u16* __restrict__ FKb, const u16* __restrict__ FVb,
    const int* __restrict__ idxb, const float* __restrict__ distb,
    const float* __restrict__ bk, const float* __restrict__ bv,
    u16* __restrict__ O)
{
    int bn = blockIdx.x;
    int b  = bn >> 9;
    int tid = threadIdx.x;
    int wv = tid >> 6, lane = tid & 63;

    __shared__ float qlds[NH][104];   // 96 + pad(8): float4-aligned, 2-way banks max
    __shared__ int   s_idx[KNN];
    __shared__ float s_dist[KNN];
    __shared__ float s_sc[NH][68];    // stride 68: (4h+j)%32 -> <=2-way on write
    __shared__ float s_att[NH][68];
    __shared__ float s_qh[NH][2];
    __shared__ float s_sd[NH];

    // ---- A: stage
    if (tid < KNN) {
        s_idx[tid]  = idxb[(size_t)bn * KNN + tid];
        s_dist[tid] = distb[(size_t)bn * KNN + tid];
    }
    const float* qrow = FQ + (size_t)bn * DIM;
    {
        int d = tid;
        if (d < DIM) qlds[d / HDIM][d % HDIM] = qrow[d];
        int d2 = tid + 512;
        if (d2 < DIM) qlds[d2 / HDIM][d2 % HDIM] = qrow[d2];
    }
    __syncthreads();

    // ---- B: qwdk / qck per head (wave wv handles head wv)
    {
        int h = wv;
        const u16* wdk = FKb + (size_t)MROWS * DIM + h * HDIM;
        const u16* ckr = FKb + (size_t)(MROWS + 1) * DIM + h * HDIM;
        const float* bkh = bk + h * HDIM;
        float q = qlds[h][lane];
        float pw = q * bf2f(wdk[lane]);
        float pc = q * (bf2f(ckr[lane]) + bkh[lane]);
        if (lane < HDIM - 64) {
            float q2 = qlds[h][lane + 64];
            pw = fmaf(q2, bf2f(wdk[lane + 64]), pw);
            pc = fmaf(q2, bf2f(ckr[lane + 64]) + bkh[lane + 64], pc);
        }
#pragma unroll
        for (int off = 32; off; off >>= 1) {
            pw += __shfl_xor(pw, off);
            pc += __shfl_xor(pc, off);
        }
        if (lane == 0) { s_qh[h][0] = pw; s_qh[h][1] = pc; }
    }

    // ---- C: raw scores, no cross-lane ops
    {
        int j = tid >> 3, h = tid & 7;
        const u16* kr = FKb + (size_t)(b * NPTS + s_idx[j]) * DIM + h * HDIM;
        float a0 = 0.f, a1 = 0.f, a2 = 0.f, a3 = 0.f;
#pragma unroll
        for (int i = 0; i < 12; ++i) {
            short8 kv = *(const short8*)&kr[i * 8];
            float4 qa = *(const float4*)&qlds[h][i * 8];
            float4 qb = *(const float4*)&qlds[h][i * 8 + 4];
            a0 = fmaf(qa.x, bf2f((u16)kv[0]), a0);
            a1 = fmaf(qa.y, bf2f((u16)kv[1]), a1);
            a2 = fmaf(qa.z, bf2f((u16)kv[2]), a2);
            a3 = fmaf(qa.w, bf2f((u16)kv[3]), a3);
            a0 = fmaf(qb.x, bf2f((u16)kv[4]), a0);
            a1 = fmaf(qb.y, bf2f((u16)kv[5]), a1);
            a2 = fmaf(qb.z, bf2f((u16)kv[6]), a2);
            a3 = fmaf(qb.w, bf2f((u16)kv[7]), a3);
        }
        s_sc[h][j] = (a0 + a1) + (a2 + a3);
    }
    __syncthreads();

    // ---- D: softmax, wave wv = head, lane = neighbor j
    {
        int h = wv, j = lane;
        const float invs = 0.10206207261596575f;  // 1/sqrt(96)
        float qwdk = s_qh[h][0], qck = s_qh[h][1];
        float dj = s_dist[j];
        float sc = (s_sc[h][j] + dj * qwdk + qck) * invs;
        float mx = sc;
#pragma unroll
        for (int off = 32; off; off >>= 1) mx = fmaxf(mx, __shfl_xor(mx, off));
        float ev = __expf(sc - mx);
        float sum = ev;
#pragma unroll
        for (int off = 32; off; off >>= 1) sum += __shfl_xor(sum, off);
        float att = ev / sum;
        s_att[h][j] = att;
        float sd = att * dj;
#pragma unroll
        for (int off = 32; off; off >>= 1) sd += __shfl_xor(sd, off);
        if (lane == 0) s_sd[h] = sd;
    }
    __syncthreads();

    // ---- E: PV, threads 0..383 own (2t, 2t+1)
    if (tid < 384) {
        int d0 = tid * 2;
        int h  = d0 / HDIM;          // pair never straddles a head (96 even)
        const float* attp = s_att[h];
        const size_t basev = (size_t)(b * NPTS) * DIM + d0;
        float o0 = 0.f, o1 = 0.f;
#pragma unroll 4
        for (int j = 0; j < KNN; ++j) {
            unsigned pv = *(const unsigned*)&FVb[basev + (size_t)s_idx[j] * DIM];
            float a = attp[j];
            o0 = fmaf(a, __uint_as_float(pv << 16), o0);
            o1 = fmaf(a, __uint_as_float(pv & 0xffff0000u), o1);
        }
        const u16* wdv = FVb + (size_t)MROWS * DIM;
        const u16* cvr = FVb + (size_t)(MROWS + 1) * DIM;
        float sdh = s_sd[h];
        o0 += sdh * bf2f(wdv[d0])     + (bf2f(cvr[d0])     + bv[d0]);
        o1 += sdh * bf2f(wdv[d0 + 1]) + (bf2f(cvr[d0 + 1]) + bv[d0 + 1]);
        unsigned po = f2bf(o0) | (f2bf(o1) << 16);
        *(unsigned*)&O[(size_t)bn * DIM + d0] = po;
    }
}

// ---------------------------------------------------------------------------
// LayerNorm + SiLU per row of 768.
// ---------------------------------------------------------------------------
__global__ __launch_bounds__(256) void ln_silu_k(
    const float* __restrict__ Z, const float* __restrict__ g,
    const float* __restrict__ bta, float* __restrict__ out)
{
    int bn = blockIdx.x, tid = threadIdx.x;
    const float* z = Z + (size_t)bn * DIM;
    int e0 = tid * 3;
    float x0 = z[e0], x1 = z[e0 + 1], x2 = z[e0 + 2];
    float s = x0 + x1 + x2;
    float ss = x0 * x0 + x1 * x1 + x2 * x2;
    __shared__ float red[4][2];
#pragma unroll
    for (int off = 32; off; off >>= 1) {
        s  += __shfl_xor(s, off);
        ss += __shfl_xor(ss, off);
    }
    int w = tid >> 6;
    if ((tid & 63) == 0) { red[w][0] = s; red[w][1] = ss; }
    __syncthreads();
    s  = red[0][0] + red[1][0] + red[2][0] + red[3][0];
    ss = red[0][1] + red[1][1] + red[2][1] + red[3][1];
    float mean = s * (1.0f / DIM);
    float var  = ss * (1.0f / DIM) - mean * mean;
    float rstd = rsqrtf(var + 1e-5f);
    float* orow = out + (size_t)bn * DIM;
#pragma unroll
    for (int i = 0; i < 3; ++i) {
        int e = e0 + i;
        float x = (i == 0) ? x0 : (i == 1) ? x1 : x2;
        float y = (x - mean) * rstd * g[e] + bta[e];
        orow[e] = y / (1.0f + __expf(-y));
    }
}

// ---------------------------------------------------------------------------
extern "C" void kernel_launch(void* const* d_in, const int* in_sizes, int n_in,
                              void* d_out, int out_size, void* d_ws, size_t ws_size,
                              hipStream_t stream)
{
    const float* features = (const float*)d_in[0];
    const float* pts      = (const float*)d_in[1];
    const float* Wd       = (const float*)d_in[2];
    const float* bd       = (const float*)d_in[3];
    const float* Wq       = (const float*)d_in[4];
    const float* bq       = (const float*)d_in[5];
    const float* Wk       = (const float*)d_in[6];
    const float* bk       = (const float*)d_in[7];
    const float* Wv       = (const float*)d_in[8];
    const float* bv       = (const float*)d_in[9];
    const float* Wo       = (const float*)d_in[10];
    const float* bo       = (const float*)d_in[11];
    const float* We       = (const float*)d_in[12];
    const float* be       = (const float*)d_in[13];
    const float* g_ln     = (const float*)d_in[14];
    const float* b_ln     = (const float*)d_in[15];

    const size_t MAT  = (size_t)MROWS * DIM;   // 786432
    const size_t MATP = (size_t)MPAD  * DIM;   // 835584

    float* ws = (float*)d_ws;
    float* FQ    = ws;                       // [1088][768] f32; rows 0..1023 reused as Z
    u16*   FKb   = (u16*)(ws + MATP);        // [1088][768] bf16 (rows 1024/1025 = wdk/ck)
    u16*   FVb   = FKb + MATP;               // [1088][768] bf16 (rows 1024/1025 = wdv/cv)
    u16*   Fb    = FVb + MATP;               // [1088][768] bf16 (features + Wd/bd rows)
    u16*   Ob    = Fb + MATP;                // [1024][768] bf16 (attention output)
    u16*   Wob   = Ob + MAT;                 // [832][768] bf16 ([Wo; bo; 0])
    u16*   W3    = Wob + (size_t)WOROWS * DIM;  // 5 x [768][768] bf16 transposed
    u16*   WeffT = W3 + 5 * WSQ;             // [768][768] bf16 (Wo@WeBot)^T
    float* c_e   = (float*)(WeffT + WSQ);    // [768] f32 (bo@WeBot)
    int*   idxb  = (int*)(c_e + DIM);
    float* distb = (float*)(idxb + (size_t)MROWS * KNN);
    float* Z     = FQ;

    // 1) all independent prep in one launch
    mega_prep_k<<<3184, 256, 0, stream>>>(features, pts, Wd, bd, Wq, Wk, Wv, Wo, bo, We,
                                          Fb, Wob, W3, idxb, distb);
    // 2) QKV projections + Weff precompute, one launch
    gemm_qkvw_k<<<dim3(12, 17, 4), 256, 0, stream>>>(
        Fb, Wob, W3, bq, FQ, FKb, FVb, WeffT, c_e);
    // 3) fused neighbor attention
    attn_k<<<MROWS, 512, 0, stream>>>(FQ, FKb, FVb, idxb, distb, bk, bv, Ob);
    // 4) Z = Fb@WeTopT + Ob@WeffT + (c_e + be)
    gemm_final_k<<<dim3(12, 16), 256, 0, stream>>>(
        Fb, Ob, W3 + 3 * WSQ, WeffT, c_e, be, Z);
    // 5) LayerNorm + SiLU
    ln_silu_k<<<MROWS, 256, 0, stream>>>(Z, g_ln, b_ln, (float*)d_out);
}

// Round 7
// 78.977 us; speedup vs baseline: 3.8274x; 1.3241x over previous
//
#include <hip/hip_runtime.h>
#include <math.h>

#define NPTS 512
#define DIM  768
#define KNN  64
#define NH   8
#define HDIM 96
#define MROWS 1024   // B*NP
#define MPAD  1088   // MROWS + 2 (Wd,bd rows) padded to 64
#define WOROWS 832   // 768 Wo rows + 1 bo row, padded to 64
#define WSQ   ((size_t)DIM * DIM)

typedef unsigned short u16;
typedef __attribute__((ext_vector_type(8))) short short8;
typedef __attribute__((ext_vector_type(4))) float f32x4;

__device__ __forceinline__ unsigned f2bf(float f) {
    unsigned u = __float_as_uint(f);
    return (u + 0x7fffu + ((u >> 16) & 1u)) >> 16;   // round-to-nearest-even
}
__device__ __forceinline__ float bf2f(u16 v) {
    return __uint_as_float(((unsigned)v) << 16);
}

// ---------------------------------------------------------------------------
// Prep kernel (pure converts): one launch.
//  [0,768)     : features fp32 -> bf16 (Fb rows 0..1023)
//  [768,816)   : Fb rows 1024(Wd) 1025(bd) 1026..1087(zero)
//  [816,1440)  : Wob = bf16([Wo; bo; 0...])  (832x768)
//  [1440,2160) : 5 transposes fp32[k][n] -> bf16 [n][k]: Wq,Wk,Wv,WeTop,WeBot
// ---------------------------------------------------------------------------
__global__ __launch_bounds__(256) void mega_prep_k(
    const float* __restrict__ features,
    const float* __restrict__ Wd, const float* __restrict__ bd,
    const float* __restrict__ Wq, const float* __restrict__ Wk, const float* __restrict__ Wv,
    const float* __restrict__ Wo, const float* __restrict__ bo, const float* __restrict__ We,
    u16* __restrict__ Fb, u16* __restrict__ Wob, u16* __restrict__ W3)
{
    __shared__ float T[64][65];
    int bid = blockIdx.x, tid = threadIdx.x;

    if (bid < 768) {                       // ---- convF
        int i = (bid * 256 + tid) * 4;
        float4 v = *(const float4*)&features[i];
        uint2 o;
        o.x = f2bf(v.x) | (f2bf(v.y) << 16);
        o.y = f2bf(v.z) | (f2bf(v.w) << 16);
        *(uint2*)&Fb[i] = o;
        return;
    }
    if (bid < 816) {                       // ---- extra A rows
        int flat = (bid - 768) * 1024 + tid * 4;   // 64x768 region
        int r = flat / DIM, c = flat - r * DIM;
        uint2 o; o.x = 0u; o.y = 0u;
        if (r == 0) {
            float4 v = *(const float4*)&Wd[c];
            o.x = f2bf(v.x) | (f2bf(v.y) << 16);
            o.y = f2bf(v.z) | (f2bf(v.w) << 16);
        } else if (r == 1) {
            float4 v = *(const float4*)&bd[c];
            o.x = f2bf(v.x) | (f2bf(v.y) << 16);
            o.y = f2bf(v.z) | (f2bf(v.w) << 16);
        }
        *(uint2*)&Fb[(size_t)(MROWS + r) * DIM + c] = o;
        return;
    }
    if (bid < 1440) {                      // ---- Wob = [Wo; bo; zeros]
        int flat = (bid - 816) * 1024 + tid * 4;   // 832x768 region
        int r = flat / DIM, c = flat - r * DIM;
        uint2 o; o.x = 0u; o.y = 0u;
        if (r < DIM) {
            float4 v = *(const float4*)&Wo[(size_t)r * DIM + c];
            o.x = f2bf(v.x) | (f2bf(v.y) << 16);
            o.y = f2bf(v.z) | (f2bf(v.w) << 16);
        } else if (r == DIM) {
            float4 v = *(const float4*)&bo[c];
            o.x = f2bf(v.x) | (f2bf(v.y) << 16);
            o.y = f2bf(v.z) | (f2bf(v.w) << 16);
        }
        *(uint2*)&Wob[(size_t)r * DIM + c] = o;
        return;
    }
    // ---- convT: 5 matrices x 144 (12x12) tile-blocks
    {
        int t = bid - 1440;
        int m = t / 144, r2 = t % 144;
        int by = r2 / 12, bx = r2 % 12;
        const float* S = (m == 0) ? Wq : (m == 1) ? Wk : (m == 2) ? Wv
                       : (m == 3) ? We : (We + WSQ);
        u16* D = W3 + (size_t)m * WSQ;
        int r0 = by * 64, c0 = bx * 64;
#pragma unroll
        for (int i = 0; i < 16; ++i) {
            int lin = tid + i * 256;
            int r = lin >> 6, c = lin & 63;
            T[r][c] = S[(size_t)(r0 + r) * DIM + c0 + c];
        }
        __syncthreads();
#pragma unroll
        for (int i = 0; i < 16; ++i) {
            int lin = tid + i * 256;
            int c = lin >> 6, r = lin & 63;
            D[(size_t)(c0 + c) * DIM + r0 + r] = (u16)f2bf(T[r][c]);
        }
    }
}

// ---------------------------------------------------------------------------
// Combined QKV/Weff GEMM + topk launch (topk overlaps GEMM on other CUs).
//  bid < 816 : GEMM  z = bid/204, y = (bid%204)/12, x = bid%12
//    z0: FQ  = Fb @ WqT + bq   (fp32, 1024 rows)
//    z1: FKb = bf16(Fb @ WkT)  (1088 rows; rows 1024/1025 = wdk/ck)
//    z2: FVb = bf16(Fb @ WvT)  (1088 rows)
//    z3: WeffT = ([Wo;bo] @ WeBotT)^T bf16; c_e = bo@WeBot row (fp32)
//  bid >= 816: topk block bn = bid-816 (bitonic over 512 keys)
// ---------------------------------------------------------------------------
union alignas(16) GTSm {
    struct { short As[64][72]; short Bs[64][72]; } g;                   // 18432 B
    struct { float P[NPTS * 3]; unsigned long long keys[NPTS]; } tk;    // 10240 B
};

__global__ __launch_bounds__(256) void qkvw_topk_k(
    const u16* __restrict__ Fb, const u16* __restrict__ Wob, const u16* __restrict__ W3,
    const float* __restrict__ bq, const float* __restrict__ pts,
    float* __restrict__ FQ, u16* __restrict__ FKb, u16* __restrict__ FVb,
    u16* __restrict__ WeffT, float* __restrict__ c_e,
    int* __restrict__ idxb, float* __restrict__ distb)
{
    __shared__ GTSm sm;
    int bid = blockIdx.x, tid = threadIdx.x;

    if (bid >= 816) {                      // ================= topk =================
        int bn = bid - 816;
        int b  = bn >> 9;
        int n  = bn & (NPTS - 1);
        const float* pb = pts + (size_t)b * NPTS * 3;
        for (int i = tid; i < NPTS * 3; i += 256) sm.tk.P[i] = pb[i];
        __syncthreads();
        float xn = sm.tk.P[n * 3], yn = sm.tk.P[n * 3 + 1], zn = sm.tk.P[n * 3 + 2];
        float sqn = xn * xn + yn * yn + zn * zn;
        for (int m = tid; m < NPTS; m += 256) {
            float xm = sm.tk.P[m * 3], ym = sm.tk.P[m * 3 + 1], zm = sm.tk.P[m * 3 + 2];
            float sqm = xm * xm + ym * ym + zm * zm;
            float d2 = sqn + sqm - 2.0f * (xn * xm + yn * ym + zn * zm);
            float dist = sqrtf(fmaxf(d2, 0.0f));
            sm.tk.keys[m] = (((unsigned long long)__float_as_uint(dist)) << 32) | (unsigned)m;
        }
        __syncthreads();
        for (int k = 2; k <= NPTS; k <<= 1) {
            for (int j = k >> 1; j > 0; j >>= 1) {
                for (int i = tid; i < NPTS; i += 256) {
                    int ixj = i ^ j;
                    if (ixj > i) {
                        bool asc = ((i & k) == 0);
                        unsigned long long a = sm.tk.keys[i], bb = sm.tk.keys[ixj];
                        if ((a > bb) == asc) { sm.tk.keys[i] = bb; sm.tk.keys[ixj] = a; }
                    }
                }
                __syncthreads();
            }
        }
        if (tid < KNN) {
            unsigned long long kk = sm.tk.keys[tid];
            idxb[(size_t)bn * KNN + tid]  = (int)(kk & 0xffffffffu);
            distb[(size_t)bn * KNN + tid] = __uint_as_float((unsigned)(kk >> 32));
        }
        return;
    }

    // ================= GEMM =================
    int z   = bid / 204;
    int rem = bid - z * 204;
    int by  = rem / 12;
    int bx  = rem - by * 12;
    if (z == 0 && by >= 16) return;
    if (z == 3 && by >= 13) return;
    const u16* A  = (z == 3) ? Wob : Fb;
    const u16* BT = W3 + (size_t)((z == 3) ? 4 : z) * WSQ;

    int wave = tid >> 6, lane = tid & 63;
    int wr = (wave >> 1) * 32, wc = (wave & 1) * 32;
    int l15 = lane & 15, kg = lane >> 4;
    int brow = by * 64, bcol = bx * 64;

    f32x4 acc[2][2] = {};

    int srow = tid >> 3;            // 0..31
    int scol = (tid & 7) * 8;       // 0,8,..,56

    for (int k0 = 0; k0 < DIM; k0 += 64) {
#pragma unroll
        for (int s = 0; s < 2; ++s) {
            int r = srow + s * 32;
            *(short8*)&sm.g.As[r][scol] = *(const short8*)&A[(size_t)(brow + r) * DIM + k0 + scol];
            *(short8*)&sm.g.Bs[r][scol] = *(const short8*)&BT[(size_t)(bcol + r) * DIM + k0 + scol];
        }
        __syncthreads();
#pragma unroll
        for (int kk = 0; kk < 2; ++kk) {
            short8 a0 = *(const short8*)&sm.g.As[wr + l15][kk * 32 + kg * 8];
            short8 a1 = *(const short8*)&sm.g.As[wr + 16 + l15][kk * 32 + kg * 8];
            short8 b0 = *(const short8*)&sm.g.Bs[wc + l15][kk * 32 + kg * 8];
            short8 b1 = *(const short8*)&sm.g.Bs[wc + 16 + l15][kk * 32 + kg * 8];
            acc[0][0] = __builtin_amdgcn_mfma_f32_16x16x32_bf16(a0, b0, acc[0][0], 0, 0, 0);
            acc[0][1] = __builtin_amdgcn_mfma_f32_16x16x32_bf16(a0, b1, acc[0][1], 0, 0, 0);
            acc[1][0] = __builtin_amdgcn_mfma_f32_16x16x32_bf16(a1, b0, acc[1][0], 0, 0, 0);
            acc[1][1] = __builtin_amdgcn_mfma_f32_16x16x32_bf16(a1, b1, acc[1][1], 0, 0, 0);
        }
        __syncthreads();
    }

    // D layout: col = lane&15, row = (lane>>4)*4 + j
#pragma unroll
    for (int m = 0; m < 2; ++m) {
#pragma unroll
        for (int n = 0; n < 2; ++n) {
            int col  = bcol + wc + n * 16 + l15;
            int row0 = brow + wr + m * 16 + kg * 4;
            if (z == 0) {
                float bv = bq[col];
#pragma unroll
                for (int j = 0; j < 4; ++j)
                    FQ[(size_t)(row0 + j) * DIM + col] = acc[m][n][j] + bv;
            } else if (z == 1) {
#pragma unroll
                for (int j = 0; j < 4; ++j)
                    FKb[(size_t)(row0 + j) * DIM + col] = (u16)f2bf(acc[m][n][j]);
            } else if (z == 2) {
#pragma unroll
                for (int j = 0; j < 4; ++j)
                    FVb[(size_t)(row0 + j) * DIM + col] = (u16)f2bf(acc[m][n][j]);
            } else {
                if (row0 + 3 < DIM) {
                    unsigned long long pk =
                          (unsigned long long)f2bf(acc[m][n][0])
                        | ((unsigned long long)f2bf(acc[m][n][1]) << 16)
                        | ((unsigned long long)f2bf(acc[m][n][2]) << 32)
                        | ((unsigned long long)f2bf(acc[m][n][3]) << 48);
                    *(unsigned long long*)&WeffT[(size_t)col * DIM + row0] = pk;
                } else {
#pragma unroll
                    for (int j = 0; j < 4; ++j) {
                        int row = row0 + j;
                        if (row < DIM)       WeffT[(size_t)col * DIM + row] = (u16)f2bf(acc[m][n][j]);
                        else if (row == DIM) c_e[col] = acc[m][n][j];
                    }
                }
            }
        }
    }
}

// ---------------------------------------------------------------------------
// Final GEMMs, z in {0,1}:
//  z0: Z0 = Fb @ WeTopT + be
//  z1: Z1 = Ob @ WeffT + c_e
// ---------------------------------------------------------------------------
__global__ __launch_bounds__(256) void gemm_final_k(
    const u16* __restrict__ Fb, const u16* __restrict__ Ob,
    const u16* __restrict__ WeTopT, const u16* __restrict__ WeffT,
    const float* __restrict__ c_e, const float* __restrict__ be,
    float* __restrict__ Z0, float* __restrict__ Z1)
{
    int z = blockIdx.z;
    const u16*   A    = z ? Ob : Fb;
    const u16*   BT   = z ? WeffT : WeTopT;
    const float* bias = z ? c_e : be;
    float*       Z    = z ? Z1 : Z0;

    __shared__ short As[64][72];
    __shared__ short Bs[64][72];

    int tid  = threadIdx.x;
    int wave = tid >> 6, lane = tid & 63;
    int wr = (wave >> 1) * 32, wc = (wave & 1) * 32;
    int l15 = lane & 15, kg = lane >> 4;
    int brow = blockIdx.y * 64, bcol = blockIdx.x * 64;

    f32x4 acc[2][2] = {};

    int srow = tid >> 3;
    int scol = (tid & 7) * 8;

    for (int k0 = 0; k0 < DIM; k0 += 64) {
#pragma unroll
        for (int s = 0; s < 2; ++s) {
            int r = srow + s * 32;
            *(short8*)&As[r][scol] = *(const short8*)&A[(size_t)(brow + r) * DIM + k0 + scol];
            *(short8*)&Bs[r][scol] = *(const short8*)&BT[(size_t)(bcol + r) * DIM + k0 + scol];
        }
        __syncthreads();
#pragma unroll
        for (int kk = 0; kk < 2; ++kk) {
            short8 a0 = *(const short8*)&As[wr + l15][kk * 32 + kg * 8];
            short8 a1 = *(const short8*)&As[wr + 16 + l15][kk * 32 + kg * 8];
            short8 b0 = *(const short8*)&Bs[wc + l15][kk * 32 + kg * 8];
            short8 b1 = *(const short8*)&Bs[wc + 16 + l15][kk * 32 + kg * 8];
            acc[0][0] = __builtin_amdgcn_mfma_f32_16x16x32_bf16(a0, b0, acc[0][0], 0, 0, 0);
            acc[0][1] = __builtin_amdgcn_mfma_f32_16x16x32_bf16(a0, b1, acc[0][1], 0, 0, 0);
            acc[1][0] = __builtin_amdgcn_mfma_f32_16x16x32_bf16(a1, b0, acc[1][0], 0, 0, 0);
            acc[1][1] = __builtin_amdgcn_mfma_f32_16x16x32_bf16(a1, b1, acc[1][1], 0, 0, 0);
        }
        __syncthreads();
    }

#pragma unroll
    for (int m = 0; m < 2; ++m) {
#pragma unroll
        for (int n = 0; n < 2; ++n) {
            int col = bcol + wc + n * 16 + l15;
            float bv = bias[col];
#pragma unroll
            for (int j = 0; j < 4; ++j) {
                int row = brow + wr + m * 16 + kg * 4 + j;
                Z[(size_t)row * DIM + col] = acc[m][n][j] + bv;
            }
        }
    }
}

// ---------------------------------------------------------------------------
// Fused neighbor attention, shuffle-free score phase. 512 threads/block.
// ---------------------------------------------------------------------------
__global__ __launch_bounds__(512) void attn_k(
    const float* __restrict__ FQ, const u16* __restrict__ FKb, const u16* __restrict__ FVb,
    const int* __restrict__ idxb, const float* __restrict__ distb,
    const float* __restrict__ bk, const float* __restrict__ bv,
    u16* __restrict__ O)
{
    int bn = blockIdx.x;
    int b  = bn >> 9;
    int tid = threadIdx.x;
    int wv = tid >> 6, lane = tid & 63;

    __shared__ float qlds[NH][104];   // 96 + pad(8): float4-aligned
    __shared__ int   s_idx[KNN];
    __shared__ float s_dist[KNN];
    __shared__ float s_sc[NH][68];
    __shared__ float s_att[NH][68];
    __shared__ float s_qh[NH][2];
    __shared__ float s_sd[NH];

    // ---- A: stage
    if (tid < KNN) {
        s_idx[tid]  = idxb[(size_t)bn * KNN + tid];
        s_dist[tid] = distb[(size_t)bn * KNN + tid];
    }
    const float* qrow = FQ + (size_t)bn * DIM;
    {
        int d = tid;
        if (d < DIM) qlds[d / HDIM][d % HDIM] = qrow[d];
        int d2 = tid + 512;
        if (d2 < DIM) qlds[d2 / HDIM][d2 % HDIM] = qrow[d2];
    }
    __syncthreads();

    // ---- B: qwdk / qck per head (wave wv handles head wv)
    {
        int h = wv;
        const u16* wdk = FKb + (size_t)MROWS * DIM + h * HDIM;
        const u16* ckr = FKb + (size_t)(MROWS + 1) * DIM + h * HDIM;
        const float* bkh = bk + h * HDIM;
        float q = qlds[h][lane];
        float pw = q * bf2f(wdk[lane]);
        float pc = q * (bf2f(ckr[lane]) + bkh[lane]);
        if (lane < HDIM - 64) {
            float q2 = qlds[h][lane + 64];
            pw = fmaf(q2, bf2f(wdk[lane + 64]), pw);
            pc = fmaf(q2, bf2f(ckr[lane + 64]) + bkh[lane + 64], pc);
        }
#pragma unroll
        for (int off = 32; off; off >>= 1) {
            pw += __shfl_xor(pw, off);
            pc += __shfl_xor(pc, off);
        }
        if (lane == 0) { s_qh[h][0] = pw; s_qh[h][1] = pc; }
    }

    // ---- C: raw scores, no cross-lane ops, u32 bf16-pair converts
    {
        int j = tid >> 3, h = tid & 7;
        const u16* kr = FKb + (size_t)(b * NPTS + s_idx[j]) * DIM + h * HDIM;
        const uint4* kr4 = (const uint4*)kr;
        float a0 = 0.f, a1 = 0.f, a2 = 0.f, a3 = 0.f;
#pragma unroll
        for (int i = 0; i < 12; ++i) {
            uint4 kv = kr4[i];
            float4 qa = *(const float4*)&qlds[h][i * 8];
            float4 qb = *(const float4*)&qlds[h][i * 8 + 4];
            a0 = fmaf(qa.x, __uint_as_float(kv.x << 16), a0);
            a1 = fmaf(qa.y, __uint_as_float(kv.x & 0xffff0000u), a1);
            a2 = fmaf(qa.z, __uint_as_float(kv.y << 16), a2);
            a3 = fmaf(qa.w, __uint_as_float(kv.y & 0xffff0000u), a3);
            a0 = fmaf(qb.x, __uint_as_float(kv.z << 16), a0);
            a1 = fmaf(qb.y, __uint_as_float(kv.z & 0xffff0000u), a1);
            a2 = fmaf(qb.z, __uint_as_float(kv.w << 16), a2);
            a3 = fmaf(qb.w, __uint_as_float(kv.w & 0xffff0000u), a3);
        }
        s_sc[h][j] = (a0 + a1) + (a2 + a3);
    }
    __syncthreads();

    // ---- D: softmax, wave wv = head, lane = neighbor j
    {
        int h = wv, j = lane;
        const float invs = 0.10206207261596575f;  // 1/sqrt(96)
        float qwdk = s_qh[h][0], qck = s_qh[h][1];
        float dj = s_dist[j];
        float sc = (s_sc[h][j] + dj * qwdk + qck) * invs;
        float mx = sc;
#pragma unroll
        for (int off = 32; off; off >>= 1) mx = fmaxf(mx, __shfl_xor(mx, off));
        float ev = __expf(sc - mx);
        float sum = ev;
#pragma unroll
        for (int off = 32; off; off >>= 1) sum += __shfl_xor(sum, off);
        float att = ev / sum;
        s_att[h][j] = att;
        float sd = att * dj;
#pragma unroll
        for (int off = 32; off; off >>= 1) sd += __shfl_xor(sd, off);
        if (lane == 0) s_sd[h] = sd;
    }
    __syncthreads();

    // ---- E: PV, threads 0..383 own (2t, 2t+1)
    if (tid < 384) {
        int d0 = tid * 2;
        int h  = d0 / HDIM;          // pair never straddles a head (96 even)
        const float* attp = s_att[h];
        const size_t basev = (size_t)(b * NPTS) * DIM + d0;
        float o0 = 0.f, o1 = 0.f;
#pragma unroll 4
        for (int j = 0; j < KNN; ++j) {
            unsigned pv = *(const unsigned*)&FVb[basev + (size_t)s_idx[j] * DIM];
            float a = attp[j];
            o0 = fmaf(a, __uint_as_float(pv << 16), o0);
            o1 = fmaf(a, __uint_as_float(pv & 0xffff0000u), o1);
        }
        const u16* wdv = FVb + (size_t)MROWS * DIM;
        const u16* cvr = FVb + (size_t)(MROWS + 1) * DIM;
        float sdh = s_sd[h];
        o0 += sdh * bf2f(wdv[d0])     + (bf2f(cvr[d0])     + bv[d0]);
        o1 += sdh * bf2f(wdv[d0 + 1]) + (bf2f(cvr[d0 + 1]) + bv[d0 + 1]);
        unsigned po = f2bf(o0) | (f2bf(o1) << 16);
        *(unsigned*)&O[(size_t)bn * DIM + d0] = po;
    }
}

// ---------------------------------------------------------------------------
// LayerNorm + SiLU per row of 768; input = Z0 + Z1.
// ---------------------------------------------------------------------------
__global__ __launch_bounds__(256) void ln_silu_k(
    const float* __restrict__ Z0, const float* __restrict__ Z1,
    const float* __restrict__ g, const float* __restrict__ bta,
    float* __restrict__ out)
{
    int bn = blockIdx.x, tid = threadIdx.x;
    const float* z0 = Z0 + (size_t)bn * DIM;
    const float* z1 = Z1 + (size_t)bn * DIM;
    int e0 = tid * 3;
    float x0 = z0[e0] + z1[e0];
    float x1 = z0[e0 + 1] + z1[e0 + 1];
    float x2 = z0[e0 + 2] + z1[e0 + 2];
    float s = x0 + x1 + x2;
    float ss = x0 * x0 + x1 * x1 + x2 * x2;
    __shared__ float red[4][2];
#pragma unroll
    for (int off = 32; off; off >>= 1) {
        s  += __shfl_xor(s, off);
        ss += __shfl_xor(ss, off);
    }
    int w = tid >> 6;
    if ((tid & 63) == 0) { red[w][0] = s; red[w][1] = ss; }
    __syncthreads();
    s  = red[0][0] + red[1][0] + red[2][0] + red[3][0];
    ss = red[0][1] + red[1][1] + red[2][1] + red[3][1];
    float mean = s * (1.0f / DIM);
    float var  = ss * (1.0f / DIM) - mean * mean;
    float rstd = rsqrtf(var + 1e-5f);
    float* orow = out + (size_t)bn * DIM;
#pragma unroll
    for (int i = 0; i < 3; ++i) {
        int e = e0 + i;
        float x = (i == 0) ? x0 : (i == 1) ? x1 : x2;
        float y = (x - mean) * rstd * g[e] + bta[e];
        orow[e] = y / (1.0f + __expf(-y));
    }
}

// ---------------------------------------------------------------------------
extern "C" void kernel_launch(void* const* d_in, const int* in_sizes, int n_in,
                              void* d_out, int out_size, void* d_ws, size_t ws_size,
                              hipStream_t stream)
{
    const float* features = (const float*)d_in[0];
    const float* pts      = (const float*)d_in[1];
    const float* Wd       = (const float*)d_in[2];
    const float* bd       = (const float*)d_in[3];
    const float* Wq       = (const float*)d_in[4];
    const float* bq       = (const float*)d_in[5];
    const float* Wk       = (const float*)d_in[6];
    const float* bk       = (const float*)d_in[7];
    const float* Wv       = (const float*)d_in[8];
    const float* bv       = (const float*)d_in[9];
    const float* Wo       = (const float*)d_in[10];
    const float* bo       = (const float*)d_in[11];
    const float* We       = (const float*)d_in[12];
    const float* be       = (const float*)d_in[13];
    const float* g_ln     = (const float*)d_in[14];
    const float* b_ln     = (const float*)d_in[15];

    const size_t MAT  = (size_t)MROWS * DIM;   // 786432
    const size_t MATP = (size_t)MPAD  * DIM;   // 835584

    float* ws = (float*)d_ws;
    float* FQ    = ws;                       // [1088][768] f32; reused as Z0 after attn
    u16*   FKb   = (u16*)(ws + MATP);        // [1088][768] bf16; FKb..FVb reused as Z1
    u16*   FVb   = FKb + MATP;               // [1088][768] bf16
    u16*   Fb    = FVb + MATP;               // [1088][768] bf16 (features + Wd/bd rows)
    u16*   Ob    = Fb + MATP;                // [1024][768] bf16 (attention output)
    u16*   Wob   = Ob + MAT;                 // [832][768] bf16 ([Wo; bo; 0])
    u16*   W3    = Wob + (size_t)WOROWS * DIM;  // 5 x [768][768] bf16 transposed
    u16*   WeffT = W3 + 5 * WSQ;             // [768][768] bf16 (Wo@WeBot)^T
    float* c_e   = (float*)(WeffT + WSQ);    // [768] f32 (bo@WeBot)
    int*   idxb  = (int*)(c_e + DIM);
    float* distb = (float*)(idxb + (size_t)MROWS * KNN);
    float* Z0    = FQ;                       // Fb@WeTopT + be
    float* Z1    = (float*)FKb;              // Ob@WeffT + c_e (3MB, spans FKb+FVb)

    // 1) pure-convert prep
    mega_prep_k<<<2160, 256, 0, stream>>>(features, Wd, bd, Wq, Wk, Wv, Wo, bo, We,
                                          Fb, Wob, W3);
    // 2) QKV projections + Weff precompute + topk, one launch (topk overlaps GEMM)
    qkvw_topk_k<<<1840, 256, 0, stream>>>(
        Fb, Wob, W3, bq, pts, FQ, FKb, FVb, WeffT, c_e, idxb, distb);
    // 3) fused neighbor attention
    attn_k<<<MROWS, 512, 0, stream>>>(FQ, FKb, FVb, idxb, distb, bk, bv, Ob);
    // 4) Z0 = Fb@WeTopT + be ; Z1 = Ob@WeffT + c_e
    gemm_final_k<<<dim3(12, 16, 2), 256, 0, stream>>>(
        Fb, Ob, W3 + 3 * WSQ, WeffT, c_e, be, Z0, Z1);
    // 5) LayerNorm(Z0+Z1) + SiLU
    ln_silu_k<<<MROWS, 256, 0, stream>>>(Z0, Z1, g_ln, b_ln, (float*)d_out);
}